// Round 9
// baseline (183.922 us; speedup 1.0000x reference)
//
#include <hip/hip_runtime.h>
#include <hip/hip_bf16.h>

// AdaBiD R9: attack kl_mfma's latency ceiling (R8 profile: 44us, all pipes
// <15% busy -> dependency-bound). Changes vs R8:
//  - kl: JS 8->16 (3072 blocks, occupancy cap 56->100%), double-buffered
//    T1/T2 mask LDS (breaks iteration WAR chain), fully unrolled 6-iter
//    j-loop (compiler hoists all independent loads).
//  - fused_mlp: reverted to the proven R6 256-thr/one-tile shape (R8's
//    512-thr 2-tile version coincided with a +22us regression).
// Pipeline: K1 prep_all (softmax/logp/frags/repack/smalls, dtype sniff),
// K2 kl_mfma (flash-style split-bf16 KL threshold + bidirectional agg),
// K3 fused_mlp (kl-partial reduce -> c, 6 MLP layers, transposed store).

namespace {

constexpr int Bn = 8, Nn = 1536, TOUT = 12;
constexpr int Mrows = Bn * Nn;   // 12288
constexpr int JS = 16;           // j-split in kl
constexpr int JT = 6;            // j-tiles per split (96/16)

typedef __attribute__((ext_vector_type(8))) short bf8;
typedef __attribute__((ext_vector_type(4))) float f4;
typedef unsigned short ush;

__device__ __forceinline__ float b2f(__hip_bfloat16 v) { return __bfloat162float(v); }
__device__ __forceinline__ ush f2bu(float f) {
  union { __hip_bfloat16 h; ush u; } c; c.h = __float2bfloat16(f); return c.u;
}
__device__ __forceinline__ float bu2f(ush u) {
  union { unsigned int i; float f; } c; c.i = ((unsigned)u) << 16; return c.f;
}
__device__ __forceinline__ float ldraw(const void* p, size_t i, int fl) {
  return fl ? ((const float*)p)[i] : b2f(((const __hip_bfloat16*)p)[i]);
}

// block-local dtype sniff: bf16 N(0,1) never has exp-field >= 140; f32 read
// as ushorts has ~45% of low-halves >= 140.  4096 samples.
__device__ __forceinline__ int detect_fl(const void* x, int tid) {
  __shared__ int cnt;
  if (tid == 0) cnt = 0;
  __syncthreads();
  const ush* u = (const ush*)x;
  int c = 0;
#pragma unroll
  for (int s = 0; s < 16; ++s) {
    ush v = u[tid + s * 256];
    if (((v >> 7) & 0xFF) >= 140) c++;
  }
  atomicAdd(&cnt, c);
  __syncthreads();
  return (cnt > 64) ? 1 : 0;
}

struct SmallTab { const void* src[16]; int n[16]; int off[16]; };
struct RepTab { const void* src[8]; int Nc[8]; int NCT[8]; int lb[9]; };

// ---------------- K1: prep + repack + smalls ---------------------------------
__global__ __launch_bounds__(256) void prep_all(
    const void* __restrict__ xraw, SmallTab st, RepTab rt,
    int* __restrict__ flag, float* __restrict__ CS,
    float* __restrict__ xT, float* __restrict__ sd,
    ush* __restrict__ pA, ush* __restrict__ lA,
    ush* __restrict__ Pk, ush* __restrict__ Xc, ush* __restrict__ Wf) {
  int tid = threadIdx.x;
  int fl = detect_fl(xraw, tid);
  int blk = blockIdx.x;

  if (blk < 48) {
    // ---- prep role: one thread per (b,n) row ----
    int row = blk * 256 + tid;
    int b = row / Nn, n = row - b * Nn;
    float xv[12];
#pragma unroll
    for (int t = 0; t < 12; ++t)
      xv[t] = ldraw(xraw, (size_t)(b * 12 + t) * Nn + n, fl);
    float mx = xv[0];
#pragma unroll
    for (int t = 1; t < 12; ++t) mx = fmaxf(mx, xv[t]);
    float e[12], Z = 0.f;
#pragma unroll
    for (int t = 0; t < 12; ++t) { e[t] = expf(xv[t] - mx); Z += e[t]; }
    float invZ = 1.f / Z;
    float sacc = 0.f;
    ush pa[32], la[32], pk[64];
#pragma unroll
    for (int k = 0; k < 32; ++k) { pa[k] = 0; la[k] = 0; }
#pragma unroll
    for (int k = 0; k < 64; ++k) pk[k] = 0;
#pragma unroll
    for (int t = 0; t < 12; ++t) {
      float pv = e[t] * invZ;
      float lv = logf(pv + 1e-10f);
      sacc += pv * lv;
      xT[(size_t)row * 12 + t] = xv[t];
      ush phv = f2bu(pv);  float plv = pv - bu2f(phv);
      ush lhv = f2bu(lv);  float llv = lv - bu2f(lhv);
      pa[t] = phv; pa[16 + t] = f2bu(plv);
      la[t] = lhv; la[16 + t] = f2bu(llv);
      pk[t] = lhv;            // [0:16)  lhi
      pk[16 + t] = f2bu(llv); // [16:32) llo
      pk[32 + t] = phv;       // [32:48) phi
      pk[48 + t] = f2bu(plv); // [48:64) plo
      Xc[((size_t)(b * 16 + t)) * Nn + n] = f2bu(xv[t]);
    }
    Xc[((size_t)(b * 16 + 12)) * Nn + n] = 0x3F80;  // ones col -> degrees
#pragma unroll
    for (int t = 13; t < 16; ++t) Xc[((size_t)(b * 16 + t)) * Nn + n] = 0;
    sd[row] = sacc;
    {
      uint4* d = (uint4*)(pA + (size_t)row * 32);
      const uint4* s = (const uint4*)pa;
      d[0] = s[0]; d[1] = s[1]; d[2] = s[2]; d[3] = s[3];
      uint4* d2 = (uint4*)(lA + (size_t)row * 32);
      const uint4* s2 = (const uint4*)la;
      d2[0] = s2[0]; d2[1] = s2[1]; d2[2] = s2[2]; d2[3] = s2[3];
      uint4* d3 = (uint4*)(Pk + (size_t)row * 64);
      const uint4* s3 = (const uint4*)pk;
#pragma unroll
      for (int v = 0; v < 8; ++v) d3[v] = s3[v];
    }
  } else if (blk < 146) {
    // ---- repack role: weights -> MFMA B-frag order ----
    int idx = (blk - 48) * 256 + tid;
    if (idx >= rt.lb[8]) return;
    int mi = 0;
#pragma unroll
    for (int i = 1; i < 8; ++i) if (idx >= rt.lb[i]) mi = i;
    int li = idx - rt.lb[mi];
    int NCT = rt.NCT[mi], Nc = rt.Nc[mi];
    int per = NCT * 64;
    int c0 = li / per, rem = li - c0 * per;
    int ct = rem >> 6, l = rem & 63;
    int q = l >> 4, m = l & 15;
    int col = ct * 16 + m;
    ush* d = Wf + (size_t)idx * 8;
#pragma unroll
    for (int j = 0; j < 8; ++j) {
      int k = c0 * 32 + q * 8 + j;
      d[j] = (col < Nc) ? f2bu(ldraw(rt.src[mi], (size_t)k * Nc + col, fl)) : 0;
    }
  } else {
    // ---- smalls role: canonicalize biases/BN params + publish flag ----
    for (int i = 0; i < 16; ++i)
      for (int e = tid; e < st.n[i]; e += 256)
        CS[st.off[i] + e] = ldraw(st.src[i], e, fl);
    if (tid == 0) flag[0] = fl;
  }
}

// ---------------- K2: kl via MFMA (flash-style) ------------------------------
// 3072 blocks = 8 b x 24 ig x 16 js. Block 256 = 4 waves; wave owns a 16-row
// i-tile, loops 6 j-tiles (fully unrolled; loads hoisted by compiler).
// S1 = p_i . lp_j via split-bf16 (hi/lo), S2 = lp_i . p_j likewise.
// A1=(self_i-S1<.5)=A[i,j], A2=(self_j-S2<.5)=A[j,i]; aggregate both against
// X' (cols 0..11 = x, col 12 = ones -> row/col degrees). Mask C->A-frag
// conversion through DOUBLE-BUFFERED wave-private LDS (jb=jt&1) so
// consecutive iterations' roundtrips overlap instead of WAR-serializing.
__global__ __launch_bounds__(256) void kl_mfma(
    const ush* __restrict__ pA, const ush* __restrict__ lA,
    const ush* __restrict__ Pk, const ush* __restrict__ Xc,
    const float* __restrict__ sd,
    float* __restrict__ psf, float* __restrict__ psb) {
  __shared__ ush T1[2][4][512], T2[2][4][512];
  int tid = threadIdx.x, w = tid >> 6, l = tid & 63, q = l >> 4, n = l & 15;
  int blk = blockIdx.x;
  int b = blk / 384, rem = blk % 384, ig = rem >> 4, js = rem & 15;
  int i0 = ig * 64 + w * 16;
  int rowb = b * Nn;

  if (q >= 2) {  // zero the k>=16 pad of both mask buffers once
    uint4 z4 = {0, 0, 0, 0};
    *(uint4*)(&T1[0][w][(size_t)l * 8]) = z4;
    *(uint4*)(&T1[1][w][(size_t)l * 8]) = z4;
    *(uint4*)(&T2[0][w][(size_t)l * 8]) = z4;
    *(uint4*)(&T2[1][w][(size_t)l * 8]) = z4;
  }

  bf8 z8 = {0, 0, 0, 0, 0, 0, 0, 0};
  bf8 aP = *(const bf8*)(pA + ((size_t)(rowb + i0 + n)) * 32 + q * 8);
  bf8 aL = *(const bf8*)(lA + ((size_t)(rowb + i0 + n)) * 32 + q * 8);
  bf8 aPh = (q < 2) ? aP : z8;
  bf8 aLh = (q < 2) ? aL : z8;
  float selfI[4];
#pragma unroll
  for (int r = 0; r < 4; ++r) selfI[r] = sd[rowb + i0 + q * 4 + r];

  f4 accF = {0.f, 0.f, 0.f, 0.f}, accB = {0.f, 0.f, 0.f, 0.f};

#pragma unroll
  for (int jt = 0; jt < JT; ++jt) {
    int jb = jt & 1;
    int jl = js * 96 + jt * 16;
    const ush* pb = Pk + ((size_t)(rowb + jl + n)) * 64 + (q & 1) * 8;
    bf8 bLh = *(const bf8*)(pb);
    bf8 bLo = *(const bf8*)(pb + 16);
    bf8 bPh = *(const bf8*)(pb + 32);
    bf8 bPo = *(const bf8*)(pb + 48);
    float selfJ = sd[rowb + jl + n];
    bf8 xfr = (q < 2)
        ? *(const bf8*)(Xc + ((size_t)(b * 16 + n)) * Nn + jl + q * 8) : z8;

    f4 s1 = {0.f, 0.f, 0.f, 0.f}, s2 = {0.f, 0.f, 0.f, 0.f};
    s1 = __builtin_amdgcn_mfma_f32_16x16x32_bf16(aP, bLh, s1, 0, 0, 0);
    s1 = __builtin_amdgcn_mfma_f32_16x16x32_bf16(aPh, bLo, s1, 0, 0, 0);
    s2 = __builtin_amdgcn_mfma_f32_16x16x32_bf16(aL, bPh, s2, 0, 0, 0);
    s2 = __builtin_amdgcn_mfma_f32_16x16x32_bf16(aLh, bPo, s2, 0, 0, 0);

    int qk = n >> 3, kj = n & 7;
#pragma unroll
    for (int r = 0; r < 4; ++r) {
      int pos = (qk * 16 + q * 4 + r) * 8 + kj;
      T1[jb][w][pos] = (selfI[r] - s1[r] < 0.5f) ? (ush)0x3F80 : (ush)0;
      T2[jb][w][pos] = (selfJ - s2[r] < 0.5f) ? (ush)0x3F80 : (ush)0;
    }
    bf8 af1 = *(const bf8*)(&T1[jb][w][(size_t)l * 8]);
    bf8 af2 = *(const bf8*)(&T2[jb][w][(size_t)l * 8]);
    accF = __builtin_amdgcn_mfma_f32_16x16x32_bf16(af1, xfr, accF, 0, 0, 0);
    accB = __builtin_amdgcn_mfma_f32_16x16x32_bf16(af2, xfr, accB, 0, 0, 0);
  }
#pragma unroll
  for (int r = 0; r < 4; ++r) {
    size_t o = ((size_t)js * Mrows + rowb + i0 + q * 4 + r) * 16 + n;
    psf[o] = accF[r];
    psb[o] = accB[r];
  }
}

// ---------------- K3: fused MLP, 4 waves / 16-row tile (R6 shape) ------------
// LDS frag layout (lane-major): slot(c0, l)*8+j holds A[m=l&15][k=(l>>4)*8+j].
// Wave w handles col-tiles {2w,2w+1} for N=128 layers, {w} for N=64 layer,
// K-split for the N=12 tail. Barriers between layers.
__global__ __launch_bounds__(256) void fused_mlp(
    const float* __restrict__ xT,
    const float* __restrict__ psf, const float* __restrict__ psb,
    const float* __restrict__ CS, const ush* __restrict__ Wf,
    const int* __restrict__ flag, void* __restrict__ outp) {
  __shared__ float xs[16][12], ccs[16][12];
  __shared__ float sfs[16][16], sbs[16][16];
  __shared__ float ws1[64], ws2[64];
  __shared__ ush hf[2048], hg[2048], xf[1024];
  __shared__ f4 red[4][64];

  int tid = threadIdx.x, w = tid >> 6, l = tid & 63, q = l >> 4, n = l & 15;
  int r0 = blockIdx.x * 16;

  // --- init: xs, W1/W2, and kl-partial reduction -> sfs/sbs ----------------
  {
    int r = tid >> 4, t = tid & 15;
    float a = 0.f, b = 0.f;
#pragma unroll
    for (int js = 0; js < JS; ++js) {
      size_t o = ((size_t)js * Mrows + r0 + r) * 16 + t;
      a += psf[o];
      b += psb[o];
    }
    sfs[r][t] = a;
    sbs[r][t] = b;
    if (tid < 128) { if (tid < 64) ws1[tid] = CS[tid]; else ws2[tid - 64] = CS[tid]; }
    if (tid < 192) {
      int rr = tid / 12, tt = tid - rr * 12;
      xs[rr][tt] = xT[(size_t)(r0 + rr) * 12 + tt];
    }
  }
  __syncthreads();
  if (tid < 192) {
    int rr = tid / 12, tt = tid - rr * 12;
    float irs = 1.f / fmaxf(sfs[rr][12], 1e-6f);
    float ics = 1.f / fmaxf(sbs[rr][12], 1e-6f);
    ccs[rr][tt] = 3.0f * (0.3f * sfs[rr][tt] * irs + 0.7f * sbs[rr][tt] * ics);
  }
  __syncthreads();

  // z A-frag regen: row = r0+n, k = c0*32 + q*8 + j
  auto zregen = [&](int c0) -> bf8 {
    int t = c0 >> 1, h0 = (c0 & 1) * 32 + q * 8;
    float xv = xs[n][t], cv = ccs[n][t];
    union { bf8 v; ush u[8]; } au;
#pragma unroll
    for (int j = 0; j < 8; ++j)
      au.u[j] = f2bu(fmaxf(fmaf(xv, ws1[h0 + j], cv * ws2[h0 + j]), 0.f));
    return au.v;
  };
  // C-layout -> frag-slot store position for col-tile ct
  auto fpos = [&](int ct, int r) -> int {
    return ((ct >> 1) * 64 + ((ct & 1) * 2 + (n >> 3)) * 16 + q * 4 + r) * 8 + (n & 7);
  };

  // --- L1e: h1 = relu(z @ ew1 + b1), N=128, wave does ct = 2w, 2w+1 --------
  {
    f4 a0 = {0.f, 0.f, 0.f, 0.f}, a1 = {0.f, 0.f, 0.f, 0.f};
    for (int c0 = 0; c0 < 24; ++c0) {
      bf8 a = zregen(c0);
      const ush* wb = Wf + ((size_t)(c0 * 8 + 2 * w) * 64 + l) * 8;
      bf8 b0 = *(const bf8*)wb;
      bf8 b1 = *(const bf8*)(wb + 512);
      a0 = __builtin_amdgcn_mfma_f32_16x16x32_bf16(a, b0, a0, 0, 0, 0);
      a1 = __builtin_amdgcn_mfma_f32_16x16x32_bf16(a, b1, a1, 0, 0, 0);
    }
#pragma unroll
    for (int u2 = 0; u2 < 2; ++u2) {
      int ct = 2 * w + u2;
      f4 acc = u2 ? a1 : a0;
      float bz = CS[128 + ct * 16 + n];
#pragma unroll
      for (int r = 0; r < 4; ++r)
        hf[fpos(ct, r)] = f2bu(fmaxf(acc[r] + bz, 0.f));
    }
  }
  __syncthreads();

  // --- L2e: h2 = relu(h1 @ ew2 + b2), K=128 --------------------------------
  {
    f4 a0 = {0.f, 0.f, 0.f, 0.f}, a1 = {0.f, 0.f, 0.f, 0.f};
    for (int c0 = 0; c0 < 4; ++c0) {
      bf8 a = *(const bf8*)(&hf[(size_t)(c0 * 64 + l) * 8]);
      const ush* wb = Wf + 98304 + ((size_t)(c0 * 8 + 2 * w) * 64 + l) * 8;
      bf8 b0 = *(const bf8*)wb;
      bf8 b1 = *(const bf8*)(wb + 512);
      a0 = __builtin_amdgcn_mfma_f32_16x16x32_bf16(a, b0, a0, 0, 0, 0);
      a1 = __builtin_amdgcn_mfma_f32_16x16x32_bf16(a, b1, a1, 0, 0, 0);
    }
#pragma unroll
    for (int u2 = 0; u2 < 2; ++u2) {
      int ct = 2 * w + u2;
      f4 acc = u2 ? a1 : a0;
      float bz = CS[256 + ct * 16 + n];
#pragma unroll
      for (int r = 0; r < 4; ++r)
        hg[fpos(ct, r)] = f2bu(fmaxf(acc[r] + bz, 0.f));
    }
  }
  __syncthreads();

  // --- L3e: xe = BN(h2 @ ew3 + b3 + z @ eproj), N=64, wave does ct = w -----
  {
    f4 a3 = {0.f, 0.f, 0.f, 0.f};
    for (int c0 = 0; c0 < 4; ++c0) {
      bf8 a = *(const bf8*)(&hg[(size_t)(c0 * 64 + l) * 8]);
      bf8 b = *(const bf8*)(Wf + 114688 + ((size_t)(c0 * 4 + w) * 64 + l) * 8);
      a3 = __builtin_amdgcn_mfma_f32_16x16x32_bf16(a, b, a3, 0, 0, 0);
    }
    for (int c0 = 0; c0 < 24; ++c0) {
      bf8 a = zregen(c0);
      bf8 b = *(const bf8*)(Wf + 122880 + ((size_t)(c0 * 4 + w) * 64 + l) * 8);
      a3 = __builtin_amdgcn_mfma_f32_16x16x32_bf16(a, b, a3, 0, 0, 0);
    }
    int col = w * 16 + n;
    float g = CS[448 + col], be = CS[512 + col], mm = CS[576 + col], vv = CS[640 + col];
    float sc = g / sqrtf(vv + 1e-5f);
    float sh = be - mm * sc;
    float bz = CS[384 + col];
#pragma unroll
    for (int r = 0; r < 4; ++r)
      xf[fpos(w, r)] = f2bu((a3[r] + bz) * sc + sh);
  }
  __syncthreads();

  // --- L1d: g1 = relu(xe @ dw1 + b1), K=64, N=128 --------------------------
  {
    f4 a0 = {0.f, 0.f, 0.f, 0.f}, a1 = {0.f, 0.f, 0.f, 0.f};
    for (int c0 = 0; c0 < 2; ++c0) {
      bf8 a = *(const bf8*)(&xf[(size_t)(c0 * 64 + l) * 8]);
      const ush* wb = Wf + 172032 + ((size_t)(c0 * 8 + 2 * w) * 64 + l) * 8;
      bf8 b0 = *(const bf8*)wb;
      bf8 b1 = *(const bf8*)(wb + 512);
      a0 = __builtin_amdgcn_mfma_f32_16x16x32_bf16(a, b0, a0, 0, 0, 0);
      a1 = __builtin_amdgcn_mfma_f32_16x16x32_bf16(a, b1, a1, 0, 0, 0);
    }
    __syncthreads();   // hf rewrite fence (L2e reads of hf are complete)
#pragma unroll
    for (int u2 = 0; u2 < 2; ++u2) {
      int ct = 2 * w + u2;
      f4 acc = u2 ? a1 : a0;
      float bz = CS[704 + ct * 16 + n];
#pragma unroll
      for (int r = 0; r < 4; ++r)
        hf[fpos(ct, r)] = f2bu(fmaxf(acc[r] + bz, 0.f));
    }
  }
  __syncthreads();

  // --- L2d: g2 = relu(g1 @ dw2 + b2), K=128 --------------------------------
  {
    f4 a0 = {0.f, 0.f, 0.f, 0.f}, a1 = {0.f, 0.f, 0.f, 0.f};
    for (int c0 = 0; c0 < 4; ++c0) {
      bf8 a = *(const bf8*)(&hf[(size_t)(c0 * 64 + l) * 8]);
      const ush* wb = Wf + 180224 + ((size_t)(c0 * 8 + 2 * w) * 64 + l) * 8;
      bf8 b0 = *(const bf8*)wb;
      bf8 b1 = *(const bf8*)(wb + 512);
      a0 = __builtin_amdgcn_mfma_f32_16x16x32_bf16(a, b0, a0, 0, 0, 0);
      a1 = __builtin_amdgcn_mfma_f32_16x16x32_bf16(a, b1, a1, 0, 0, 0);
    }
    __syncthreads();   // hg rewrite fence
#pragma unroll
    for (int u2 = 0; u2 < 2; ++u2) {
      int ct = 2 * w + u2;
      f4 acc = u2 ? a1 : a0;
      float bz = CS[832 + ct * 16 + n];
#pragma unroll
      for (int r = 0; r < 4; ++r)
        hg[fpos(ct, r)] = f2bu(fmaxf(acc[r] + bz, 0.f));
    }
  }
  __syncthreads();

  // --- L3d: out = BN(g2 @ dw3 + b3 + xe @ dproj), N=12; K-split 4 waves ----
  {
    f4 ao = {0.f, 0.f, 0.f, 0.f};
    {  // dw3 chunk c0 = w  (K=128 -> 4 chunks)
      bf8 a = *(const bf8*)(&hg[(size_t)(w * 64 + l) * 8]);
      bf8 b = *(const bf8*)(Wf + 196608 + ((size_t)w * 64 + l) * 8);
      ao = __builtin_amdgcn_mfma_f32_16x16x32_bf16(a, b, ao, 0, 0, 0);
    }
    if (w < 2) {  // dproj chunk c0 = w  (K=64 -> 2 chunks)
      bf8 a = *(const bf8*)(&xf[(size_t)(w * 64 + l) * 8]);
      bf8 b = *(const bf8*)(Wf + 198656 + ((size_t)w * 64 + l) * 8);
      ao = __builtin_amdgcn_mfma_f32_16x16x32_bf16(a, b, ao, 0, 0, 0);
    }
    red[w][l] = ao;
  }
  __syncthreads();
  if (w == 0) {
    f4 s = red[0][l] + red[1][l] + red[2][l] + red[3][l];
    int fl = flag[0];
    if (n < 12) {
      float bz = CS[960 + n];
      float g = CS[972 + n], be = CS[984 + n], mm = CS[996 + n], vv = CS[1008 + n];
      float sc = g / sqrtf(vv + 1e-5f);
      float sh = be - mm * sc;
#pragma unroll
      for (int r = 0; r < 4; ++r) {
        int row = r0 + q * 4 + r;
        int bb = row / Nn, nn = row - bb * Nn;
        size_t oi = ((size_t)bb * TOUT + n) * Nn + nn;
        float ov = (s[r] + bz) * sc + sh;
        if (fl) ((float*)outp)[oi] = ov;
        else    ((ush*)outp)[oi] = f2bu(ov);
      }
    }
  }
}

}  // namespace

extern "C" void kernel_launch(void* const* d_in, const int* in_sizes, int n_in,
                              void* d_out, int out_size, void* d_ws, size_t ws_size,
                              hipStream_t stream) {
  float* f = (float*)d_ws;
  int* flag = (int*)d_ws;                 // f[0..15]
  float* CS  = f + 16;                    // 1020 small params (f32)
  float* xT  = f + 1040;                  // 147456
  float* sd  = f + 148496;                // 12288
  float* psf = f + 160784;                // 16*12288*16 = 3145728
  float* psb = f + 3306512;               // 3145728
  ush* U = (ush*)(f + 6452240);
  ush* pA    = U;                         // 12288*32
  ush* lA    = U + 393216;                // 12288*32
  ush* Pk    = U + 786432;                // 12288*64 packed b-frags
  ush* Xc    = U + 1572864;               // 8*16*1536
  ush* Wf    = U + 1769472;               // 199680

  SmallTab st;
  {
    const int idxs[16] = {1, 2, 4, 6, 8, 10, 11, 12, 13, 15, 17, 19, 21, 22, 23, 24};
    const int ns[16]   = {64, 64, 128, 128, 64, 64, 64, 64, 64, 128, 128, 12, 12, 12, 12, 12};
    int off = 0;
    for (int i = 0; i < 16; ++i) {
      st.src[i] = d_in[idxs[i]]; st.n[i] = ns[i]; st.off[i] = off; off += ns[i];
    }
  }
  RepTab rt;
  {
    const int idxs[8]  = {3, 5, 7, 9, 14, 16, 18, 20};
    const int rNc[8]   = {128, 128, 64, 64, 128, 128, 12, 12};
    const int rNCT[8]  = {8, 8, 4, 4, 8, 8, 1, 1};
    const int rlb[9]   = {0, 12288, 14336, 15360, 21504, 22528, 24576, 24832, 24960};
    for (int i = 0; i < 8; ++i) {
      rt.src[i] = d_in[idxs[i]]; rt.Nc[i] = rNc[i]; rt.NCT[i] = rNCT[i];
    }
    for (int i = 0; i < 9; ++i) rt.lb[i] = rlb[i];
  }

  prep_all<<<147, 256, 0, stream>>>(d_in[0], st, rt, flag, CS, xT, sd,
                                    pA, lA, Pk, Xc, Wf);
  kl_mfma<<<3072, 256, 0, stream>>>(pA, lA, Pk, Xc, sd, psf, psb);
  fused_mlp<<<768, 256, 0, stream>>>(xT, psf, psb, CS, Wf, flag, d_out);
}

// Round 10
// 178.799 us; speedup vs baseline: 1.0287x; 1.0287x over previous
//
#include <hip/hip_runtime.h>
#include <hip/hip_bf16.h>

// AdaBiD R10: kl mask transpose via __ballot instead of LDS. MI355X gfx950.
// R9 evidence: kl is LDS-pipe-throughput-bound (8-way-conflicted scalar mask
// writes + conflicted b128 reads ~ 60k cyc/CU); occupancy/unroll knobs were
// neutral-to-negative. Fix: the 0/1 mask tile lives in 4 wave-uniform 64-bit
// ballots (v_cmp output); each lane extracts its 8 consecutive A-frag bits
// with a cndmask tree + 64-bit shift + bit->bf16 expansion. kl LDS usage = 0.
// Everything else reverted to the measured-best R6 configuration (JS=8,
// fused_mlp 256-thr one-tile).
// Pipeline: K1 prep_all (softmax/logp/frags/repack/smalls, dtype sniff),
// K2 kl_mfma (flash-style split-bf16 KL threshold + bidirectional agg),
// K3 fused_mlp (kl-partial reduce -> c, 6 MLP layers, transposed store).

namespace {

constexpr int Bn = 8, Nn = 1536, TOUT = 12;
constexpr int Mrows = Bn * Nn;   // 12288
constexpr int JS = 8;            // j-split in kl

typedef __attribute__((ext_vector_type(8))) short bf8;
typedef __attribute__((ext_vector_type(4))) float f4;
typedef unsigned short ush;

__device__ __forceinline__ float b2f(__hip_bfloat16 v) { return __bfloat162float(v); }
__device__ __forceinline__ ush f2bu(float f) {
  union { __hip_bfloat16 h; ush u; } c; c.h = __float2bfloat16(f); return c.u;
}
__device__ __forceinline__ float bu2f(ush u) {
  union { unsigned int i; float f; } c; c.i = ((unsigned)u) << 16; return c.f;
}
__device__ __forceinline__ float ldraw(const void* p, size_t i, int fl) {
  return fl ? ((const float*)p)[i] : b2f(((const __hip_bfloat16*)p)[i]);
}

// block-local dtype sniff: bf16 N(0,1) never has exp-field >= 140; f32 read
// as ushorts has ~45% of low-halves >= 140.  4096 samples.
__device__ __forceinline__ int detect_fl(const void* x, int tid) {
  __shared__ int cnt;
  if (tid == 0) cnt = 0;
  __syncthreads();
  const ush* u = (const ush*)x;
  int c = 0;
#pragma unroll
  for (int s = 0; s < 16; ++s) {
    ush v = u[tid + s * 256];
    if (((v >> 7) & 0xFF) >= 140) c++;
  }
  atomicAdd(&cnt, c);
  __syncthreads();
  return (cnt > 64) ? 1 : 0;
}

// Ballot-encoded 16x16 mask -> A-frag (lane q,n holds M[n][q*8+j], j=0..7;
// zeros for k>=16). B_r bit(q*16+c) = M[q*4+r][c]; target bits are the
// consecutive run [(n>>2)*16 + q*8, +8) of B_{n&3}.
__device__ __forceinline__ bf8 expand_mask(
    unsigned long long b0, unsigned long long b1,
    unsigned long long b2, unsigned long long b3, int n, int q) {
  unsigned long long bb = (n & 2) ? ((n & 1) ? b3 : b2) : ((n & 1) ? b1 : b0);
  int sh = ((n >> 2) << 4) + ((q & 1) << 3);      // q&1 keeps shift < 64
  unsigned byte = (q < 2) ? ((unsigned)(bb >> sh) & 0xFFu) : 0u;
  union { bf8 v; unsigned u[4]; } out;
#pragma unroll
  for (int jj = 0; jj < 4; ++jj) {
    unsigned two = byte >> (jj * 2);
    out.u[jj] = ((two & 1u) ? 0x3F80u : 0u) | ((two & 2u) ? 0x3F800000u : 0u);
  }
  return out.v;
}

struct SmallTab { const void* src[16]; int n[16]; int off[16]; };
struct RepTab { const void* src[8]; int Nc[8]; int NCT[8]; int lb[9]; };

// ---------------- K1: prep + repack + smalls ---------------------------------
__global__ __launch_bounds__(256) void prep_all(
    const void* __restrict__ xraw, SmallTab st, RepTab rt,
    int* __restrict__ flag, float* __restrict__ CS,
    float* __restrict__ xT, float* __restrict__ sd,
    ush* __restrict__ pA, ush* __restrict__ lA,
    ush* __restrict__ Pk, ush* __restrict__ Xc, ush* __restrict__ Wf) {
  int tid = threadIdx.x;
  int fl = detect_fl(xraw, tid);
  int blk = blockIdx.x;

  if (blk < 48) {
    // ---- prep role: one thread per (b,n) row ----
    int row = blk * 256 + tid;
    int b = row / Nn, n = row - b * Nn;
    float xv[12];
#pragma unroll
    for (int t = 0; t < 12; ++t)
      xv[t] = ldraw(xraw, (size_t)(b * 12 + t) * Nn + n, fl);
    float mx = xv[0];
#pragma unroll
    for (int t = 1; t < 12; ++t) mx = fmaxf(mx, xv[t]);
    float e[12], Z = 0.f;
#pragma unroll
    for (int t = 0; t < 12; ++t) { e[t] = expf(xv[t] - mx); Z += e[t]; }
    float invZ = 1.f / Z;
    float sacc = 0.f;
    ush pa[32], la[32], pk[64];
#pragma unroll
    for (int k = 0; k < 32; ++k) { pa[k] = 0; la[k] = 0; }
#pragma unroll
    for (int k = 0; k < 64; ++k) pk[k] = 0;
#pragma unroll
    for (int t = 0; t < 12; ++t) {
      float pv = e[t] * invZ;
      float lv = logf(pv + 1e-10f);
      sacc += pv * lv;
      xT[(size_t)row * 12 + t] = xv[t];
      ush phv = f2bu(pv);  float plv = pv - bu2f(phv);
      ush lhv = f2bu(lv);  float llv = lv - bu2f(lhv);
      pa[t] = phv; pa[16 + t] = f2bu(plv);
      la[t] = lhv; la[16 + t] = f2bu(llv);
      pk[t] = lhv;            // [0:16)  lhi
      pk[16 + t] = f2bu(llv); // [16:32) llo
      pk[32 + t] = phv;       // [32:48) phi
      pk[48 + t] = f2bu(plv); // [48:64) plo
      Xc[((size_t)(b * 16 + t)) * Nn + n] = f2bu(xv[t]);
    }
    Xc[((size_t)(b * 16 + 12)) * Nn + n] = 0x3F80;  // ones col -> degrees
#pragma unroll
    for (int t = 13; t < 16; ++t) Xc[((size_t)(b * 16 + t)) * Nn + n] = 0;
    sd[row] = sacc;
    {
      uint4* d = (uint4*)(pA + (size_t)row * 32);
      const uint4* s = (const uint4*)pa;
      d[0] = s[0]; d[1] = s[1]; d[2] = s[2]; d[3] = s[3];
      uint4* d2 = (uint4*)(lA + (size_t)row * 32);
      const uint4* s2 = (const uint4*)la;
      d2[0] = s2[0]; d2[1] = s2[1]; d2[2] = s2[2]; d2[3] = s2[3];
      uint4* d3 = (uint4*)(Pk + (size_t)row * 64);
      const uint4* s3 = (const uint4*)pk;
#pragma unroll
      for (int v = 0; v < 8; ++v) d3[v] = s3[v];
    }
  } else if (blk < 146) {
    // ---- repack role: weights -> MFMA B-frag order ----
    int idx = (blk - 48) * 256 + tid;
    if (idx >= rt.lb[8]) return;
    int mi = 0;
#pragma unroll
    for (int i = 1; i < 8; ++i) if (idx >= rt.lb[i]) mi = i;
    int li = idx - rt.lb[mi];
    int NCT = rt.NCT[mi], Nc = rt.Nc[mi];
    int per = NCT * 64;
    int c0 = li / per, rem = li - c0 * per;
    int ct = rem >> 6, l = rem & 63;
    int q = l >> 4, m = l & 15;
    int col = ct * 16 + m;
    ush* d = Wf + (size_t)idx * 8;
#pragma unroll
    for (int j = 0; j < 8; ++j) {
      int k = c0 * 32 + q * 8 + j;
      d[j] = (col < Nc) ? f2bu(ldraw(rt.src[mi], (size_t)k * Nc + col, fl)) : 0;
    }
  } else {
    // ---- smalls role: canonicalize biases/BN params + publish flag ----
    for (int i = 0; i < 16; ++i)
      for (int e = tid; e < st.n[i]; e += 256)
        CS[st.off[i] + e] = ldraw(st.src[i], e, fl);
    if (tid == 0) flag[0] = fl;
  }
}

// ---------------- K2: kl via MFMA (flash-style, zero LDS) --------------------
// 1536 blocks = 8 b x 24 ig x 8 js. Block 256 = 4 waves; wave owns a 16-row
// i-tile, loops 12 j-tiles. S1 = p_i . lp_j via split-bf16 (hi/lo),
// S2 = lp_i . p_j likewise. A1=(self_i-S1<.5)=A[i,j], A2=(self_j-S2<.5)
// =A[j,i]; aggregate both against X' (cols 0..11 = x, col 12 = ones ->
// row/col degrees). Mask C->A-frag conversion via __ballot + VALU bit
// expansion -- no LDS, no bank conflicts, no lgkmcnt chains.
__global__ __launch_bounds__(256) void kl_mfma(
    const ush* __restrict__ pA, const ush* __restrict__ lA,
    const ush* __restrict__ Pk, const ush* __restrict__ Xc,
    const float* __restrict__ sd,
    float* __restrict__ psf, float* __restrict__ psb) {
  int tid = threadIdx.x, w = tid >> 6, l = tid & 63, q = l >> 4, n = l & 15;
  int blk = blockIdx.x;
  int b = blk / 192, rem = blk % 192, ig = rem >> 3, js = rem & 7;
  int i0 = ig * 64 + w * 16;
  int rowb = b * Nn;

  bf8 z8 = {0, 0, 0, 0, 0, 0, 0, 0};
  bf8 aP = *(const bf8*)(pA + ((size_t)(rowb + i0 + n)) * 32 + q * 8);
  bf8 aL = *(const bf8*)(lA + ((size_t)(rowb + i0 + n)) * 32 + q * 8);
  bf8 aPh = (q < 2) ? aP : z8;
  bf8 aLh = (q < 2) ? aL : z8;
  float selfI[4];
#pragma unroll
  for (int r = 0; r < 4; ++r) selfI[r] = sd[rowb + i0 + q * 4 + r];

  f4 accF = {0.f, 0.f, 0.f, 0.f}, accB = {0.f, 0.f, 0.f, 0.f};

#pragma unroll 4
  for (int jt = 0; jt < 12; ++jt) {
    int jl = js * 192 + jt * 16;
    const ush* pb = Pk + ((size_t)(rowb + jl + n)) * 64 + (q & 1) * 8;
    bf8 bLh = *(const bf8*)(pb);
    bf8 bLo = *(const bf8*)(pb + 16);
    bf8 bPh = *(const bf8*)(pb + 32);
    bf8 bPo = *(const bf8*)(pb + 48);
    float selfJ = sd[rowb + jl + n];
    bf8 xfr = (q < 2)
        ? *(const bf8*)(Xc + ((size_t)(b * 16 + n)) * Nn + jl + q * 8) : z8;

    f4 s1 = {0.f, 0.f, 0.f, 0.f}, s2 = {0.f, 0.f, 0.f, 0.f};
    s1 = __builtin_amdgcn_mfma_f32_16x16x32_bf16(aP, bLh, s1, 0, 0, 0);
    s1 = __builtin_amdgcn_mfma_f32_16x16x32_bf16(aPh, bLo, s1, 0, 0, 0);
    s2 = __builtin_amdgcn_mfma_f32_16x16x32_bf16(aL, bPh, s2, 0, 0, 0);
    s2 = __builtin_amdgcn_mfma_f32_16x16x32_bf16(aLh, bPo, s2, 0, 0, 0);

    // v_cmp -> wave-uniform ballots: B_r bit(q*16+n) = M[q*4+r][n]
    unsigned long long f0 = __ballot(selfI[0] - s1[0] < 0.5f);
    unsigned long long f1 = __ballot(selfI[1] - s1[1] < 0.5f);
    unsigned long long f2 = __ballot(selfI[2] - s1[2] < 0.5f);
    unsigned long long f3 = __ballot(selfI[3] - s1[3] < 0.5f);
    unsigned long long g0 = __ballot(selfJ - s2[0] < 0.5f);
    unsigned long long g1 = __ballot(selfJ - s2[1] < 0.5f);
    unsigned long long g2 = __ballot(selfJ - s2[2] < 0.5f);
    unsigned long long g3 = __ballot(selfJ - s2[3] < 0.5f);

    bf8 af1 = expand_mask(f0, f1, f2, f3, n, q);
    bf8 af2 = expand_mask(g0, g1, g2, g3, n, q);
    accF = __builtin_amdgcn_mfma_f32_16x16x32_bf16(af1, xfr, accF, 0, 0, 0);
    accB = __builtin_amdgcn_mfma_f32_16x16x32_bf16(af2, xfr, accB, 0, 0, 0);
  }
#pragma unroll
  for (int r = 0; r < 4; ++r) {
    size_t o = ((size_t)js * Mrows + rowb + i0 + q * 4 + r) * 16 + n;
    psf[o] = accF[r];
    psb[o] = accB[r];
  }
}

// ---------------- K3: fused MLP, 4 waves / 16-row tile (R6 shape) ------------
// LDS frag layout (lane-major): slot(c0, l)*8+j holds A[m=l&15][k=(l>>4)*8+j].
// Wave w handles col-tiles {2w,2w+1} for N=128 layers, {w} for N=64 layer,
// K-split for the N=12 tail. Barriers between layers.
__global__ __launch_bounds__(256) void fused_mlp(
    const float* __restrict__ xT,
    const float* __restrict__ psf, const float* __restrict__ psb,
    const float* __restrict__ CS, const ush* __restrict__ Wf,
    const int* __restrict__ flag, void* __restrict__ outp) {
  __shared__ float xs[16][12], ccs[16][12];
  __shared__ float sfs[16][16], sbs[16][16];
  __shared__ float ws1[64], ws2[64];
  __shared__ ush hf[2048], hg[2048], xf[1024];
  __shared__ f4 red[4][64];

  int tid = threadIdx.x, w = tid >> 6, l = tid & 63, q = l >> 4, n = l & 15;
  int r0 = blockIdx.x * 16;

  // --- init: xs, W1/W2, and kl-partial reduction -> sfs/sbs ----------------
  {
    int r = tid >> 4, t = tid & 15;
    float a = 0.f, b = 0.f;
#pragma unroll
    for (int js = 0; js < JS; ++js) {
      size_t o = ((size_t)js * Mrows + r0 + r) * 16 + t;
      a += psf[o];
      b += psb[o];
    }
    sfs[r][t] = a;
    sbs[r][t] = b;
    if (tid < 128) { if (tid < 64) ws1[tid] = CS[tid]; else ws2[tid - 64] = CS[tid]; }
    if (tid < 192) {
      int rr = tid / 12, tt = tid - rr * 12;
      xs[rr][tt] = xT[(size_t)(r0 + rr) * 12 + tt];
    }
  }
  __syncthreads();
  if (tid < 192) {
    int rr = tid / 12, tt = tid - rr * 12;
    float irs = 1.f / fmaxf(sfs[rr][12], 1e-6f);
    float ics = 1.f / fmaxf(sbs[rr][12], 1e-6f);
    ccs[rr][tt] = 3.0f * (0.3f * sfs[rr][tt] * irs + 0.7f * sbs[rr][tt] * ics);
  }
  __syncthreads();

  // z A-frag regen: row = r0+n, k = c0*32 + q*8 + j
  auto zregen = [&](int c0) -> bf8 {
    int t = c0 >> 1, h0 = (c0 & 1) * 32 + q * 8;
    float xv = xs[n][t], cv = ccs[n][t];
    union { bf8 v; ush u[8]; } au;
#pragma unroll
    for (int j = 0; j < 8; ++j)
      au.u[j] = f2bu(fmaxf(fmaf(xv, ws1[h0 + j], cv * ws2[h0 + j]), 0.f));
    return au.v;
  };
  // C-layout -> frag-slot store position for col-tile ct
  auto fpos = [&](int ct, int r) -> int {
    return ((ct >> 1) * 64 + ((ct & 1) * 2 + (n >> 3)) * 16 + q * 4 + r) * 8 + (n & 7);
  };

  // --- L1e: h1 = relu(z @ ew1 + b1), N=128, wave does ct = 2w, 2w+1 --------
  {
    f4 a0 = {0.f, 0.f, 0.f, 0.f}, a1 = {0.f, 0.f, 0.f, 0.f};
    for (int c0 = 0; c0 < 24; ++c0) {
      bf8 a = zregen(c0);
      const ush* wb = Wf + ((size_t)(c0 * 8 + 2 * w) * 64 + l) * 8;
      bf8 b0 = *(const bf8*)wb;
      bf8 b1 = *(const bf8*)(wb + 512);
      a0 = __builtin_amdgcn_mfma_f32_16x16x32_bf16(a, b0, a0, 0, 0, 0);
      a1 = __builtin_amdgcn_mfma_f32_16x16x32_bf16(a, b1, a1, 0, 0, 0);
    }
#pragma unroll
    for (int u2 = 0; u2 < 2; ++u2) {
      int ct = 2 * w + u2;
      f4 acc = u2 ? a1 : a0;
      float bz = CS[128 + ct * 16 + n];
#pragma unroll
      for (int r = 0; r < 4; ++r)
        hf[fpos(ct, r)] = f2bu(fmaxf(acc[r] + bz, 0.f));
    }
  }
  __syncthreads();

  // --- L2e: h2 = relu(h1 @ ew2 + b2), K=128 --------------------------------
  {
    f4 a0 = {0.f, 0.f, 0.f, 0.f}, a1 = {0.f, 0.f, 0.f, 0.f};
    for (int c0 = 0; c0 < 4; ++c0) {
      bf8 a = *(const bf8*)(&hf[(size_t)(c0 * 64 + l) * 8]);
      const ush* wb = Wf + 98304 + ((size_t)(c0 * 8 + 2 * w) * 64 + l) * 8;
      bf8 b0 = *(const bf8*)wb;
      bf8 b1 = *(const bf8*)(wb + 512);
      a0 = __builtin_amdgcn_mfma_f32_16x16x32_bf16(a, b0, a0, 0, 0, 0);
      a1 = __builtin_amdgcn_mfma_f32_16x16x32_bf16(a, b1, a1, 0, 0, 0);
    }
#pragma unroll
    for (int u2 = 0; u2 < 2; ++u2) {
      int ct = 2 * w + u2;
      f4 acc = u2 ? a1 : a0;
      float bz = CS[256 + ct * 16 + n];
#pragma unroll
      for (int r = 0; r < 4; ++r)
        hg[fpos(ct, r)] = f2bu(fmaxf(acc[r] + bz, 0.f));
    }
  }
  __syncthreads();

  // --- L3e: xe = BN(h2 @ ew3 + b3 + z @ eproj), N=64, wave does ct = w -----
  {
    f4 a3 = {0.f, 0.f, 0.f, 0.f};
    for (int c0 = 0; c0 < 4; ++c0) {
      bf8 a = *(const bf8*)(&hg[(size_t)(c0 * 64 + l) * 8]);
      bf8 b = *(const bf8*)(Wf + 114688 + ((size_t)(c0 * 4 + w) * 64 + l) * 8);
      a3 = __builtin_amdgcn_mfma_f32_16x16x32_bf16(a, b, a3, 0, 0, 0);
    }
    for (int c0 = 0; c0 < 24; ++c0) {
      bf8 a = zregen(c0);
      bf8 b = *(const bf8*)(Wf + 122880 + ((size_t)(c0 * 4 + w) * 64 + l) * 8);
      a3 = __builtin_amdgcn_mfma_f32_16x16x32_bf16(a, b, a3, 0, 0, 0);
    }
    int col = w * 16 + n;
    float g = CS[448 + col], be = CS[512 + col], mm = CS[576 + col], vv = CS[640 + col];
    float sc = g / sqrtf(vv + 1e-5f);
    float sh = be - mm * sc;
    float bz = CS[384 + col];
#pragma unroll
    for (int r = 0; r < 4; ++r)
      xf[fpos(w, r)] = f2bu((a3[r] + bz) * sc + sh);
  }
  __syncthreads();

  // --- L1d: g1 = relu(xe @ dw1 + b1), K=64, N=128 --------------------------
  {
    f4 a0 = {0.f, 0.f, 0.f, 0.f}, a1 = {0.f, 0.f, 0.f, 0.f};
    for (int c0 = 0; c0 < 2; ++c0) {
      bf8 a = *(const bf8*)(&xf[(size_t)(c0 * 64 + l) * 8]);
      const ush* wb = Wf + 172032 + ((size_t)(c0 * 8 + 2 * w) * 64 + l) * 8;
      bf8 b0 = *(const bf8*)wb;
      bf8 b1 = *(const bf8*)(wb + 512);
      a0 = __builtin_amdgcn_mfma_f32_16x16x32_bf16(a, b0, a0, 0, 0, 0);
      a1 = __builtin_amdgcn_mfma_f32_16x16x32_bf16(a, b1, a1, 0, 0, 0);
    }
    __syncthreads();   // hf rewrite fence (L2e reads of hf are complete)
#pragma unroll
    for (int u2 = 0; u2 < 2; ++u2) {
      int ct = 2 * w + u2;
      f4 acc = u2 ? a1 : a0;
      float bz = CS[704 + ct * 16 + n];
#pragma unroll
      for (int r = 0; r < 4; ++r)
        hf[fpos(ct, r)] = f2bu(fmaxf(acc[r] + bz, 0.f));
    }
  }
  __syncthreads();

  // --- L2d: g2 = relu(g1 @ dw2 + b2), K=128 --------------------------------
  {
    f4 a0 = {0.f, 0.f, 0.f, 0.f}, a1 = {0.f, 0.f, 0.f, 0.f};
    for (int c0 = 0; c0 < 4; ++c0) {
      bf8 a = *(const bf8*)(&hf[(size_t)(c0 * 64 + l) * 8]);
      const ush* wb = Wf + 180224 + ((size_t)(c0 * 8 + 2 * w) * 64 + l) * 8;
      bf8 b0 = *(const bf8*)wb;
      bf8 b1 = *(const bf8*)(wb + 512);
      a0 = __builtin_amdgcn_mfma_f32_16x16x32_bf16(a, b0, a0, 0, 0, 0);
      a1 = __builtin_amdgcn_mfma_f32_16x16x32_bf16(a, b1, a1, 0, 0, 0);
    }
    __syncthreads();   // hg rewrite fence
#pragma unroll
    for (int u2 = 0; u2 < 2; ++u2) {
      int ct = 2 * w + u2;
      f4 acc = u2 ? a1 : a0;
      float bz = CS[832 + ct * 16 + n];
#pragma unroll
      for (int r = 0; r < 4; ++r)
        hg[fpos(ct, r)] = f2bu(fmaxf(acc[r] + bz, 0.f));
    }
  }
  __syncthreads();

  // --- L3d: out = BN(g2 @ dw3 + b3 + xe @ dproj), N=12; K-split 4 waves ----
  {
    f4 ao = {0.f, 0.f, 0.f, 0.f};
    {  // dw3 chunk c0 = w  (K=128 -> 4 chunks)
      bf8 a = *(const bf8*)(&hg[(size_t)(w * 64 + l) * 8]);
      bf8 b = *(const bf8*)(Wf + 196608 + ((size_t)w * 64 + l) * 8);
      ao = __builtin_amdgcn_mfma_f32_16x16x32_bf16(a, b, ao, 0, 0, 0);
    }
    if (w < 2) {  // dproj chunk c0 = w  (K=64 -> 2 chunks)
      bf8 a = *(const bf8*)(&xf[(size_t)(w * 64 + l) * 8]);
      bf8 b = *(const bf8*)(Wf + 198656 + ((size_t)w * 64 + l) * 8);
      ao = __builtin_amdgcn_mfma_f32_16x16x32_bf16(a, b, ao, 0, 0, 0);
    }
    red[w][l] = ao;
  }
  __syncthreads();
  if (w == 0) {
    f4 s = red[0][l] + red[1][l] + red[2][l] + red[3][l];
    int fl = flag[0];
    if (n < 12) {
      float bz = CS[960 + n];
      float g = CS[972 + n], be = CS[984 + n], mm = CS[996 + n], vv = CS[1008 + n];
      float sc = g / sqrtf(vv + 1e-5f);
      float sh = be - mm * sc;
#pragma unroll
      for (int r = 0; r < 4; ++r) {
        int row = r0 + q * 4 + r;
        int bb = row / Nn, nn = row - bb * Nn;
        size_t oi = ((size_t)bb * TOUT + n) * Nn + nn;
        float ov = (s[r] + bz) * sc + sh;
        if (fl) ((float*)outp)[oi] = ov;
        else    ((ush*)outp)[oi] = f2bu(ov);
      }
    }
  }
}

}  // namespace

extern "C" void kernel_launch(void* const* d_in, const int* in_sizes, int n_in,
                              void* d_out, int out_size, void* d_ws, size_t ws_size,
                              hipStream_t stream) {
  float* f = (float*)d_ws;
  int* flag = (int*)d_ws;                 // f[0..15]
  float* CS  = f + 16;                    // 1020 small params (f32)
  float* xT  = f + 1040;                  // 147456
  float* sd  = f + 148496;                // 12288
  float* psf = f + 160784;                // 8*12288*16 = 1572864
  float* psb = f + 1733648;               // 1572864
  ush* U = (ush*)(f + 3306512);
  ush* pA    = U;                         // 12288*32
  ush* lA    = U + 393216;                // 12288*32
  ush* Pk    = U + 786432;                // 12288*64 packed b-frags
  ush* Xc    = U + 1572864;               // 8*16*1536
  ush* Wf    = U + 1769472;               // 199680

  SmallTab st;
  {
    const int idxs[16] = {1, 2, 4, 6, 8, 10, 11, 12, 13, 15, 17, 19, 21, 22, 23, 24};
    const int ns[16]   = {64, 64, 128, 128, 64, 64, 64, 64, 64, 128, 128, 12, 12, 12, 12, 12};
    int off = 0;
    for (int i = 0; i < 16; ++i) {
      st.src[i] = d_in[idxs[i]]; st.n[i] = ns[i]; st.off[i] = off; off += ns[i];
    }
  }
  RepTab rt;
  {
    const int idxs[8]  = {3, 5, 7, 9, 14, 16, 18, 20};
    const int rNc[8]   = {128, 128, 64, 64, 128, 128, 12, 12};
    const int rNCT[8]  = {8, 8, 4, 4, 8, 8, 1, 1};
    const int rlb[9]   = {0, 12288, 14336, 15360, 21504, 22528, 24576, 24832, 24960};
    for (int i = 0; i < 8; ++i) {
      rt.src[i] = d_in[idxs[i]]; rt.Nc[i] = rNc[i]; rt.NCT[i] = rNCT[i];
    }
    for (int i = 0; i < 9; ++i) rt.lb[i] = rlb[i];
  }

  prep_all<<<147, 256, 0, stream>>>(d_in[0], st, rt, flag, CS, xT, sd,
                                    pA, lA, Pk, Xc, Wf);
  kl_mfma<<<1536, 256, 0, stream>>>(pA, lA, Pk, Xc, sd, psf, psb);
  fused_mlp<<<768, 256, 0, stream>>>(xT, psf, psb, CS, Wf, flag, d_out);
}

// Round 11
// 161.212 us; speedup vs baseline: 1.1409x; 1.1091x over previous
//
#include <hip/hip_runtime.h>
#include <hip/hip_bf16.h>

// AdaBiD R11: kill kl's VMEM gathers. MI355X gfx950.
// R10 evidence: removing ALL kl LDS (ballot mask transpose) left dur at
// 44.4us = R8 exactly, pipes all <30% -> the shared factor is the gathered
// inner-loop loads (4x Pk: 64 lanes over 16 rows x 128B apart; Xc: 16 rows
// x 3KB apart) = address/gather-pipe bound (~370 cyc/wave-iter observed).
// Fix: pre-permute per-16-row-tile FRAGMENT arrays in prep (like the MLP
// weight repack): PkF[b][tile][arr][lane], XcF[b][tile][lane] (q>=2 slots
// pre-zeroed). kl inner loop = 5 coalesced 1KB loads + 1 sd line. Ballot
// mask expansion kept (LDS-free). fused_mlp unchanged (R6 shape).
// Pipeline: K1 prep_all, K2 kl_mfma, K3 fused_mlp.

namespace {

constexpr int Bn = 8, Nn = 1536, TOUT = 12;
constexpr int Mrows = Bn * Nn;   // 12288
constexpr int JS = 8;            // j-split in kl

typedef __attribute__((ext_vector_type(8))) short bf8;
typedef __attribute__((ext_vector_type(4))) float f4;
typedef unsigned short ush;

__device__ __forceinline__ float b2f(__hip_bfloat16 v) { return __bfloat162float(v); }
__device__ __forceinline__ ush f2bu(float f) {
  union { __hip_bfloat16 h; ush u; } c; c.h = __float2bfloat16(f); return c.u;
}
__device__ __forceinline__ float bu2f(ush u) {
  union { unsigned int i; float f; } c; c.i = ((unsigned)u) << 16; return c.f;
}
__device__ __forceinline__ float ldraw(const void* p, size_t i, int fl) {
  return fl ? ((const float*)p)[i] : b2f(((const __hip_bfloat16*)p)[i]);
}

// block-local dtype sniff: bf16 N(0,1) never has exp-field >= 140; f32 read
// as ushorts has ~45% of low-halves >= 140.  4096 samples.
__device__ __forceinline__ int detect_fl(const void* x, int tid) {
  __shared__ int cnt;
  if (tid == 0) cnt = 0;
  __syncthreads();
  const ush* u = (const ush*)x;
  int c = 0;
#pragma unroll
  for (int s = 0; s < 16; ++s) {
    ush v = u[tid + s * 256];
    if (((v >> 7) & 0xFF) >= 140) c++;
  }
  atomicAdd(&cnt, c);
  __syncthreads();
  return (cnt > 64) ? 1 : 0;
}

// Ballot-encoded 16x16 mask -> A-frag (lane q,n holds M[n][q*8+j], j=0..7;
// zeros for k>=16). B_r bit(q*16+c) = M[q*4+r][c]; target bits are the
// consecutive run [(n>>2)*16 + q*8, +8) of B_{n&3}.
__device__ __forceinline__ bf8 expand_mask(
    unsigned long long b0, unsigned long long b1,
    unsigned long long b2, unsigned long long b3, int n, int q) {
  unsigned long long bb = (n & 2) ? ((n & 1) ? b3 : b2) : ((n & 1) ? b1 : b0);
  int sh = ((n >> 2) << 4) + ((q & 1) << 3);      // q&1 keeps shift < 64
  unsigned byte = (q < 2) ? ((unsigned)(bb >> sh) & 0xFFu) : 0u;
  union { bf8 v; unsigned u[4]; } out;
#pragma unroll
  for (int jj = 0; jj < 4; ++jj) {
    unsigned two = byte >> (jj * 2);
    out.u[jj] = ((two & 1u) ? 0x3F80u : 0u) | ((two & 2u) ? 0x3F800000u : 0u);
  }
  return out.v;
}

struct SmallTab { const void* src[16]; int n[16]; int off[16]; };
struct RepTab { const void* src[8]; int Nc[8]; int NCT[8]; int lb[9]; };

// ---------------- K1: prep + repack + smalls ---------------------------------
__global__ __launch_bounds__(256) void prep_all(
    const void* __restrict__ xraw, SmallTab st, RepTab rt,
    int* __restrict__ flag, float* __restrict__ CS,
    float* __restrict__ xT, float* __restrict__ sd,
    ush* __restrict__ pA, ush* __restrict__ lA,
    ush* __restrict__ PkF, ush* __restrict__ XcF, ush* __restrict__ Wf) {
  int tid = threadIdx.x;
  int fl = detect_fl(xraw, tid);
  int blk = blockIdx.x;

  if (blk < 48) {
    // ---- prep role: one thread per (b,nn) spatial row ----
    int row = blk * 256 + tid;
    int b = row / Nn, nn = row - b * Nn;
    int tile = nn >> 4, n16 = nn & 15;
    float xv[12];
#pragma unroll
    for (int t = 0; t < 12; ++t)
      xv[t] = ldraw(xraw, (size_t)(b * 12 + t) * Nn + nn, fl);
    float mx = xv[0];
#pragma unroll
    for (int t = 1; t < 12; ++t) mx = fmaxf(mx, xv[t]);
    float e[12], Z = 0.f;
#pragma unroll
    for (int t = 0; t < 12; ++t) { e[t] = expf(xv[t] - mx); Z += e[t]; }
    float invZ = 1.f / Z;
    float sacc = 0.f;
    ush pa[32], la[32];
    ush hh[4][2][8];   // [arr][half][8]: arr 0=lhi 1=llo 2=phi 3=plo
#pragma unroll
    for (int k = 0; k < 32; ++k) { pa[k] = 0; la[k] = 0; }
#pragma unroll
    for (int a2 = 0; a2 < 4; ++a2)
#pragma unroll
      for (int h = 0; h < 2; ++h)
#pragma unroll
        for (int j = 0; j < 8; ++j) hh[a2][h][j] = 0;
#pragma unroll
    for (int t = 0; t < 12; ++t) {
      float pv = e[t] * invZ;
      float lv = logf(pv + 1e-10f);
      sacc += pv * lv;
      xT[(size_t)row * 12 + t] = xv[t];
      ush phv = f2bu(pv);  float plv = pv - bu2f(phv);
      ush lhv = f2bu(lv);  float llv = lv - bu2f(lhv);
      pa[t] = phv; pa[16 + t] = f2bu(plv);
      la[t] = lhv; la[16 + t] = f2bu(llv);
      int h = t >> 3, j = t & 7;
      hh[0][h][j] = lhv;
      hh[1][h][j] = f2bu(llv);
      hh[2][h][j] = phv;
      hh[3][h][j] = f2bu(plv);
    }
    sd[row] = sacc;
    {
      uint4* d = (uint4*)(pA + (size_t)row * 32);
      const uint4* s = (const uint4*)pa;
      d[0] = s[0]; d[1] = s[1]; d[2] = s[2]; d[3] = s[3];
      uint4* d2 = (uint4*)(lA + (size_t)row * 32);
      const uint4* s2 = (const uint4*)la;
      d2[0] = s2[0]; d2[1] = s2[1]; d2[2] = s2[2]; d2[3] = s2[3];
    }
    // PkF[b][tile][arr][lane=q*16+n16] = arr-half(q&1) of this row (16B)
    {
      size_t tb = ((size_t)(b * 96 + tile)) * 4 * 512;
#pragma unroll
      for (int a2 = 0; a2 < 4; ++a2)
#pragma unroll
        for (int qq = 0; qq < 4; ++qq)
          *(uint4*)(PkF + tb + ((size_t)a2 * 64 + qq * 16 + n16) * 8) =
              *(const uint4*)hh[a2][qq & 1];
    }
    // XcF[b][tile][lane=q*16+nf] jj-th elem = X'[feature nf][col nn], where
    // this thread's column nn sits at (q2=(nn>>3)&1, jj=nn&7); q>=2 lanes = 0.
    {
      size_t xb = ((size_t)(b * 96 + tile)) * 64 * 8;
      int q2 = (nn >> 3) & 1, jj = nn & 7;
#pragma unroll
      for (int nf = 0; nf < 16; ++nf) {
        ush v = (nf < 12) ? f2bu(xv[nf]) : ((nf == 12) ? (ush)0x3F80 : (ush)0);
        XcF[xb + ((size_t)q2 * 16 + nf) * 8 + jj] = v;
        XcF[xb + ((size_t)(q2 + 2) * 16 + nf) * 8 + jj] = 0;
      }
    }
  } else if (blk < 146) {
    // ---- repack role: weights -> MFMA B-frag order ----
    int idx = (blk - 48) * 256 + tid;
    if (idx >= rt.lb[8]) return;
    int mi = 0;
#pragma unroll
    for (int i = 1; i < 8; ++i) if (idx >= rt.lb[i]) mi = i;
    int li = idx - rt.lb[mi];
    int NCT = rt.NCT[mi], Nc = rt.Nc[mi];
    int per = NCT * 64;
    int c0 = li / per, rem = li - c0 * per;
    int ct = rem >> 6, l = rem & 63;
    int q = l >> 4, m = l & 15;
    int col = ct * 16 + m;
    ush* d = Wf + (size_t)idx * 8;
#pragma unroll
    for (int j = 0; j < 8; ++j) {
      int k = c0 * 32 + q * 8 + j;
      d[j] = (col < Nc) ? f2bu(ldraw(rt.src[mi], (size_t)k * Nc + col, fl)) : 0;
    }
  } else {
    // ---- smalls role: canonicalize biases/BN params + publish flag ----
    for (int i = 0; i < 16; ++i)
      for (int e = tid; e < st.n[i]; e += 256)
        CS[st.off[i] + e] = ldraw(st.src[i], e, fl);
    if (tid == 0) flag[0] = fl;
  }
}

// ---------------- K2: kl via MFMA (flash-style, zero LDS, coalesced) ---------
// 1536 blocks = 8 b x 24 ig x 8 js. Block 256 = 4 waves; wave owns a 16-row
// i-tile, loops 12 j-tiles. S1 = p_i . lp_j via split-bf16 (hi/lo),
// S2 = lp_i . p_j likewise. A1=(self_i-S1<.5)=A[i,j], A2=(self_j-S2<.5)
// =A[j,i]; aggregate both against X' (cols 0..11 = x, col 12 = ones ->
// row/col degrees). Mask C->A-frag via __ballot + VALU bit expansion.
// ALL inner-loop loads are lane-coalesced 1KB frag reads (PkF/XcF).
__global__ __launch_bounds__(256) void kl_mfma(
    const ush* __restrict__ pA, const ush* __restrict__ lA,
    const ush* __restrict__ PkF, const ush* __restrict__ XcF,
    const float* __restrict__ sd,
    float* __restrict__ psf, float* __restrict__ psb) {
  int tid = threadIdx.x, w = tid >> 6, l = tid & 63, q = l >> 4, n = l & 15;
  int blk = blockIdx.x;
  int b = blk / 192, rem = blk % 192, ig = rem >> 3, js = rem & 7;
  int i0 = ig * 64 + w * 16;
  int rowb = b * Nn;

  bf8 z8 = {0, 0, 0, 0, 0, 0, 0, 0};
  bf8 aP = *(const bf8*)(pA + ((size_t)(rowb + i0 + n)) * 32 + q * 8);
  bf8 aL = *(const bf8*)(lA + ((size_t)(rowb + i0 + n)) * 32 + q * 8);
  bf8 aPh = (q < 2) ? aP : z8;
  bf8 aLh = (q < 2) ? aL : z8;
  float selfI[4];
#pragma unroll
  for (int r = 0; r < 4; ++r) selfI[r] = sd[rowb + i0 + q * 4 + r];

  f4 accF = {0.f, 0.f, 0.f, 0.f}, accB = {0.f, 0.f, 0.f, 0.f};

#pragma unroll 4
  for (int jt = 0; jt < 12; ++jt) {
    int jl = js * 192 + jt * 16;
    int tile = js * 12 + jt;
    const ush* tb = PkF + ((size_t)(b * 96 + tile)) * 4 * 512 + (size_t)l * 8;
    bf8 bLh = *(const bf8*)(tb);
    bf8 bLo = *(const bf8*)(tb + 512);
    bf8 bPh = *(const bf8*)(tb + 1024);
    bf8 bPo = *(const bf8*)(tb + 1536);
    bf8 xfr = *(const bf8*)(XcF + ((size_t)(b * 96 + tile) * 64 + l) * 8);
    float selfJ = sd[rowb + jl + n];

    f4 s1 = {0.f, 0.f, 0.f, 0.f}, s2 = {0.f, 0.f, 0.f, 0.f};
    s1 = __builtin_amdgcn_mfma_f32_16x16x32_bf16(aP, bLh, s1, 0, 0, 0);
    s1 = __builtin_amdgcn_mfma_f32_16x16x32_bf16(aPh, bLo, s1, 0, 0, 0);
    s2 = __builtin_amdgcn_mfma_f32_16x16x32_bf16(aL, bPh, s2, 0, 0, 0);
    s2 = __builtin_amdgcn_mfma_f32_16x16x32_bf16(aLh, bPo, s2, 0, 0, 0);

    // v_cmp -> wave-uniform ballots: B_r bit(q*16+n) = M[q*4+r][n]
    unsigned long long f0 = __ballot(selfI[0] - s1[0] < 0.5f);
    unsigned long long f1 = __ballot(selfI[1] - s1[1] < 0.5f);
    unsigned long long f2 = __ballot(selfI[2] - s1[2] < 0.5f);
    unsigned long long f3 = __ballot(selfI[3] - s1[3] < 0.5f);
    unsigned long long g0 = __ballot(selfJ - s2[0] < 0.5f);
    unsigned long long g1 = __ballot(selfJ - s2[1] < 0.5f);
    unsigned long long g2 = __ballot(selfJ - s2[2] < 0.5f);
    unsigned long long g3 = __ballot(selfJ - s2[3] < 0.5f);

    bf8 af1 = expand_mask(f0, f1, f2, f3, n, q);
    bf8 af2 = expand_mask(g0, g1, g2, g3, n, q);
    accF = __builtin_amdgcn_mfma_f32_16x16x32_bf16(af1, xfr, accF, 0, 0, 0);
    accB = __builtin_amdgcn_mfma_f32_16x16x32_bf16(af2, xfr, accB, 0, 0, 0);
  }
#pragma unroll
  for (int r = 0; r < 4; ++r) {
    size_t o = ((size_t)js * Mrows + rowb + i0 + q * 4 + r) * 16 + n;
    psf[o] = accF[r];
    psb[o] = accB[r];
  }
}

// ---------------- K3: fused MLP, 4 waves / 16-row tile (R6 shape) ------------
// LDS frag layout (lane-major): slot(c0, l)*8+j holds A[m=l&15][k=(l>>4)*8+j].
// Wave w handles col-tiles {2w,2w+1} for N=128 layers, {w} for N=64 layer,
// K-split for the N=12 tail. Barriers between layers.
__global__ __launch_bounds__(256) void fused_mlp(
    const float* __restrict__ xT,
    const float* __restrict__ psf, const float* __restrict__ psb,
    const float* __restrict__ CS, const ush* __restrict__ Wf,
    const int* __restrict__ flag, void* __restrict__ outp) {
  __shared__ float xs[16][12], ccs[16][12];
  __shared__ float sfs[16][16], sbs[16][16];
  __shared__ float ws1[64], ws2[64];
  __shared__ ush hf[2048], hg[2048], xf[1024];
  __shared__ f4 red[4][64];

  int tid = threadIdx.x, w = tid >> 6, l = tid & 63, q = l >> 4, n = l & 15;
  int r0 = blockIdx.x * 16;

  // --- init: xs, W1/W2, and kl-partial reduction -> sfs/sbs ----------------
  {
    int r = tid >> 4, t = tid & 15;
    float a = 0.f, b = 0.f;
#pragma unroll
    for (int js = 0; js < JS; ++js) {
      size_t o = ((size_t)js * Mrows + r0 + r) * 16 + t;
      a += psf[o];
      b += psb[o];
    }
    sfs[r][t] = a;
    sbs[r][t] = b;
    if (tid < 128) { if (tid < 64) ws1[tid] = CS[tid]; else ws2[tid - 64] = CS[tid]; }
    if (tid < 192) {
      int rr = tid / 12, tt = tid - rr * 12;
      xs[rr][tt] = xT[(size_t)(r0 + rr) * 12 + tt];
    }
  }
  __syncthreads();
  if (tid < 192) {
    int rr = tid / 12, tt = tid - rr * 12;
    float irs = 1.f / fmaxf(sfs[rr][12], 1e-6f);
    float ics = 1.f / fmaxf(sbs[rr][12], 1e-6f);
    ccs[rr][tt] = 3.0f * (0.3f * sfs[rr][tt] * irs + 0.7f * sbs[rr][tt] * ics);
  }
  __syncthreads();

  // z A-frag regen: row = r0+n, k = c0*32 + q*8 + j
  auto zregen = [&](int c0) -> bf8 {
    int t = c0 >> 1, h0 = (c0 & 1) * 32 + q * 8;
    float xv = xs[n][t], cv = ccs[n][t];
    union { bf8 v; ush u[8]; } au;
#pragma unroll
    for (int j = 0; j < 8; ++j)
      au.u[j] = f2bu(fmaxf(fmaf(xv, ws1[h0 + j], cv * ws2[h0 + j]), 0.f));
    return au.v;
  };
  // C-layout -> frag-slot store position for col-tile ct
  auto fpos = [&](int ct, int r) -> int {
    return ((ct >> 1) * 64 + ((ct & 1) * 2 + (n >> 3)) * 16 + q * 4 + r) * 8 + (n & 7);
  };

  // --- L1e: h1 = relu(z @ ew1 + b1), N=128, wave does ct = 2w, 2w+1 --------
  {
    f4 a0 = {0.f, 0.f, 0.f, 0.f}, a1 = {0.f, 0.f, 0.f, 0.f};
    for (int c0 = 0; c0 < 24; ++c0) {
      bf8 a = zregen(c0);
      const ush* wb = Wf + ((size_t)(c0 * 8 + 2 * w) * 64 + l) * 8;
      bf8 b0 = *(const bf8*)wb;
      bf8 b1 = *(const bf8*)(wb + 512);
      a0 = __builtin_amdgcn_mfma_f32_16x16x32_bf16(a, b0, a0, 0, 0, 0);
      a1 = __builtin_amdgcn_mfma_f32_16x16x32_bf16(a, b1, a1, 0, 0, 0);
    }
#pragma unroll
    for (int u2 = 0; u2 < 2; ++u2) {
      int ct = 2 * w + u2;
      f4 acc = u2 ? a1 : a0;
      float bz = CS[128 + ct * 16 + n];
#pragma unroll
      for (int r = 0; r < 4; ++r)
        hf[fpos(ct, r)] = f2bu(fmaxf(acc[r] + bz, 0.f));
    }
  }
  __syncthreads();

  // --- L2e: h2 = relu(h1 @ ew2 + b2), K=128 --------------------------------
  {
    f4 a0 = {0.f, 0.f, 0.f, 0.f}, a1 = {0.f, 0.f, 0.f, 0.f};
    for (int c0 = 0; c0 < 4; ++c0) {
      bf8 a = *(const bf8*)(&hf[(size_t)(c0 * 64 + l) * 8]);
      const ush* wb = Wf + 98304 + ((size_t)(c0 * 8 + 2 * w) * 64 + l) * 8;
      bf8 b0 = *(const bf8*)wb;
      bf8 b1 = *(const bf8*)(wb + 512);
      a0 = __builtin_amdgcn_mfma_f32_16x16x32_bf16(a, b0, a0, 0, 0, 0);
      a1 = __builtin_amdgcn_mfma_f32_16x16x32_bf16(a, b1, a1, 0, 0, 0);
    }
#pragma unroll
    for (int u2 = 0; u2 < 2; ++u2) {
      int ct = 2 * w + u2;
      f4 acc = u2 ? a1 : a0;
      float bz = CS[256 + ct * 16 + n];
#pragma unroll
      for (int r = 0; r < 4; ++r)
        hg[fpos(ct, r)] = f2bu(fmaxf(acc[r] + bz, 0.f));
    }
  }
  __syncthreads();

  // --- L3e: xe = BN(h2 @ ew3 + b3 + z @ eproj), N=64, wave does ct = w -----
  {
    f4 a3 = {0.f, 0.f, 0.f, 0.f};
    for (int c0 = 0; c0 < 4; ++c0) {
      bf8 a = *(const bf8*)(&hg[(size_t)(c0 * 64 + l) * 8]);
      bf8 b = *(const bf8*)(Wf + 114688 + ((size_t)(c0 * 4 + w) * 64 + l) * 8);
      a3 = __builtin_amdgcn_mfma_f32_16x16x32_bf16(a, b, a3, 0, 0, 0);
    }
    for (int c0 = 0; c0 < 24; ++c0) {
      bf8 a = zregen(c0);
      bf8 b = *(const bf8*)(Wf + 122880 + ((size_t)(c0 * 4 + w) * 64 + l) * 8);
      a3 = __builtin_amdgcn_mfma_f32_16x16x32_bf16(a, b, a3, 0, 0, 0);
    }
    int col = w * 16 + n;
    float g = CS[448 + col], be = CS[512 + col], mm = CS[576 + col], vv = CS[640 + col];
    float sc = g / sqrtf(vv + 1e-5f);
    float sh = be - mm * sc;
    float bz = CS[384 + col];
#pragma unroll
    for (int r = 0; r < 4; ++r)
      xf[fpos(w, r)] = f2bu((a3[r] + bz) * sc + sh);
  }
  __syncthreads();

  // --- L1d: g1 = relu(xe @ dw1 + b1), K=64, N=128 --------------------------
  {
    f4 a0 = {0.f, 0.f, 0.f, 0.f}, a1 = {0.f, 0.f, 0.f, 0.f};
    for (int c0 = 0; c0 < 2; ++c0) {
      bf8 a = *(const bf8*)(&xf[(size_t)(c0 * 64 + l) * 8]);
      const ush* wb = Wf + 172032 + ((size_t)(c0 * 8 + 2 * w) * 64 + l) * 8;
      bf8 b0 = *(const bf8*)wb;
      bf8 b1 = *(const bf8*)(wb + 512);
      a0 = __builtin_amdgcn_mfma_f32_16x16x32_bf16(a, b0, a0, 0, 0, 0);
      a1 = __builtin_amdgcn_mfma_f32_16x16x32_bf16(a, b1, a1, 0, 0, 0);
    }
    __syncthreads();   // hf rewrite fence (L2e reads of hf are complete)
#pragma unroll
    for (int u2 = 0; u2 < 2; ++u2) {
      int ct = 2 * w + u2;
      f4 acc = u2 ? a1 : a0;
      float bz = CS[704 + ct * 16 + n];
#pragma unroll
      for (int r = 0; r < 4; ++r)
        hf[fpos(ct, r)] = f2bu(fmaxf(acc[r] + bz, 0.f));
    }
  }
  __syncthreads();

  // --- L2d: g2 = relu(g1 @ dw2 + b2), K=128 --------------------------------
  {
    f4 a0 = {0.f, 0.f, 0.f, 0.f}, a1 = {0.f, 0.f, 0.f, 0.f};
    for (int c0 = 0; c0 < 4; ++c0) {
      bf8 a = *(const bf8*)(&hf[(size_t)(c0 * 64 + l) * 8]);
      const ush* wb = Wf + 180224 + ((size_t)(c0 * 8 + 2 * w) * 64 + l) * 8;
      bf8 b0 = *(const bf8*)wb;
      bf8 b1 = *(const bf8*)(wb + 512);
      a0 = __builtin_amdgcn_mfma_f32_16x16x32_bf16(a, b0, a0, 0, 0, 0);
      a1 = __builtin_amdgcn_mfma_f32_16x16x32_bf16(a, b1, a1, 0, 0, 0);
    }
    __syncthreads();   // hg rewrite fence
#pragma unroll
    for (int u2 = 0; u2 < 2; ++u2) {
      int ct = 2 * w + u2;
      f4 acc = u2 ? a1 : a0;
      float bz = CS[832 + ct * 16 + n];
#pragma unroll
      for (int r = 0; r < 4; ++r)
        hg[fpos(ct, r)] = f2bu(fmaxf(acc[r] + bz, 0.f));
    }
  }
  __syncthreads();

  // --- L3d: out = BN(g2 @ dw3 + b3 + xe @ dproj), N=12; K-split 4 waves ----
  {
    f4 ao = {0.f, 0.f, 0.f, 0.f};
    {  // dw3 chunk c0 = w  (K=128 -> 4 chunks)
      bf8 a = *(const bf8*)(&hg[(size_t)(w * 64 + l) * 8]);
      bf8 b = *(const bf8*)(Wf + 196608 + ((size_t)w * 64 + l) * 8);
      ao = __builtin_amdgcn_mfma_f32_16x16x32_bf16(a, b, ao, 0, 0, 0);
    }
    if (w < 2) {  // dproj chunk c0 = w  (K=64 -> 2 chunks)
      bf8 a = *(const bf8*)(&xf[(size_t)(w * 64 + l) * 8]);
      bf8 b = *(const bf8*)(Wf + 198656 + ((size_t)w * 64 + l) * 8);
      ao = __builtin_amdgcn_mfma_f32_16x16x32_bf16(a, b, ao, 0, 0, 0);
    }
    red[w][l] = ao;
  }
  __syncthreads();
  if (w == 0) {
    f4 s = red[0][l] + red[1][l] + red[2][l] + red[3][l];
    int fl = flag[0];
    if (n < 12) {
      float bz = CS[960 + n];
      float g = CS[972 + n], be = CS[984 + n], mm = CS[996 + n], vv = CS[1008 + n];
      float sc = g / sqrtf(vv + 1e-5f);
      float sh = be - mm * sc;
#pragma unroll
      for (int r = 0; r < 4; ++r) {
        int row = r0 + q * 4 + r;
        int bb = row / Nn, nn = row - bb * Nn;
        size_t oi = ((size_t)bb * TOUT + n) * Nn + nn;
        float ov = (s[r] + bz) * sc + sh;
        if (fl) ((float*)outp)[oi] = ov;
        else    ((ush*)outp)[oi] = f2bu(ov);
      }
    }
  }
}

}  // namespace

extern "C" void kernel_launch(void* const* d_in, const int* in_sizes, int n_in,
                              void* d_out, int out_size, void* d_ws, size_t ws_size,
                              hipStream_t stream) {
  float* f = (float*)d_ws;
  int* flag = (int*)d_ws;                 // f[0..15]
  float* CS  = f + 16;                    // 1020 small params (f32)
  float* xT  = f + 1040;                  // 147456
  float* sd  = f + 148496;                // 12288
  float* psf = f + 160784;                // 8*12288*16 = 1572864
  float* psb = f + 1733648;               // 1572864
  ush* U = (ush*)(f + 3306512);
  ush* pA    = U;                         // 12288*32
  ush* lA    = U + 393216;                // 12288*32
  ush* PkF   = U + 786432;                // 8*96*4*512 = 1572864
  ush* XcF   = U + 2359296;               // 8*96*512   = 393216
  ush* Wf    = U + 2752512;               // 199680

  SmallTab st;
  {
    const int idxs[16] = {1, 2, 4, 6, 8, 10, 11, 12, 13, 15, 17, 19, 21, 22, 23, 24};
    const int ns[16]   = {64, 64, 128, 128, 64, 64, 64, 64, 64, 128, 128, 12, 12, 12, 12, 12};
    int off = 0;
    for (int i = 0; i < 16; ++i) {
      st.src[i] = d_in[idxs[i]]; st.n[i] = ns[i]; st.off[i] = off; off += ns[i];
    }
  }
  RepTab rt;
  {
    const int idxs[8]  = {3, 5, 7, 9, 14, 16, 18, 20};
    const int rNc[8]   = {128, 128, 64, 64, 128, 128, 12, 12};
    const int rNCT[8]  = {8, 8, 4, 4, 8, 8, 1, 1};
    const int rlb[9]   = {0, 12288, 14336, 15360, 21504, 22528, 24576, 24832, 24960};
    for (int i = 0; i < 8; ++i) {
      rt.src[i] = d_in[idxs[i]]; rt.Nc[i] = rNc[i]; rt.NCT[i] = rNCT[i];
    }
    for (int i = 0; i < 9; ++i) rt.lb[i] = rlb[i];
  }

  prep_all<<<147, 256, 0, stream>>>(d_in[0], st, rt, flag, CS, xT, sd,
                                    pA, lA, PkF, XcF, Wf);
  kl_mfma<<<1536, 256, 0, stream>>>(pA, lA, PkF, XcF, sd, psf, psb);
  fused_mlp<<<768, 256, 0, stream>>>(xT, psf, psb, CS, Wf, flag, d_out);
}

// Round 12
// 158.391 us; speedup vs baseline: 1.1612x; 1.0178x over previous
//
#include <hip/hip_runtime.h>
#include <hip/hip_bf16.h>

// AdaBiD R12: cut fused_mlp's z-regen VALU (compute z frags ONCE into LDS,
// reuse in L1e+L3e: ~1150 -> ~144 VALU-inst/lane) and move XcF production to
// a dedicated coalesced role in prep_all. kl unchanged (R11 coalesced-frag
// version, verified ~27us). MI355X gfx950.
// Pipeline: K1 prep_all (prep 48 | repack 98 | XcF 96 | smalls 1 blocks),
// K2 kl_mfma (flash-style split-bf16 KL threshold + bidirectional agg,
// ballot mask transpose, all loads coalesced), K3 fused_mlp (kl-partial
// reduce -> c, z->LDS, 6 MLP layers, transposed store).

namespace {

constexpr int Bn = 8, Nn = 1536, TOUT = 12;
constexpr int Mrows = Bn * Nn;   // 12288
constexpr int JS = 8;            // j-split in kl

typedef __attribute__((ext_vector_type(8))) short bf8;
typedef __attribute__((ext_vector_type(4))) float f4;
typedef unsigned short ush;

__device__ __forceinline__ float b2f(__hip_bfloat16 v) { return __bfloat162float(v); }
__device__ __forceinline__ ush f2bu(float f) {
  union { __hip_bfloat16 h; ush u; } c; c.h = __float2bfloat16(f); return c.u;
}
__device__ __forceinline__ float bu2f(ush u) {
  union { unsigned int i; float f; } c; c.i = ((unsigned)u) << 16; return c.f;
}
__device__ __forceinline__ float ldraw(const void* p, size_t i, int fl) {
  return fl ? ((const float*)p)[i] : b2f(((const __hip_bfloat16*)p)[i]);
}

// block-local dtype sniff: bf16 N(0,1) never has exp-field >= 140; f32 read
// as ushorts has ~45% of low-halves >= 140.  4096 samples.
__device__ __forceinline__ int detect_fl(const void* x, int tid) {
  __shared__ int cnt;
  if (tid == 0) cnt = 0;
  __syncthreads();
  const ush* u = (const ush*)x;
  int c = 0;
#pragma unroll
  for (int s = 0; s < 16; ++s) {
    ush v = u[tid + s * 256];
    if (((v >> 7) & 0xFF) >= 140) c++;
  }
  atomicAdd(&cnt, c);
  __syncthreads();
  return (cnt > 64) ? 1 : 0;
}

// Ballot-encoded 16x16 mask -> A-frag (lane q,n holds M[n][q*8+j], j=0..7;
// zeros for k>=16). B_r bit(q*16+c) = M[q*4+r][c]; target bits are the
// consecutive run [(n>>2)*16 + q*8, +8) of B_{n&3}.
__device__ __forceinline__ bf8 expand_mask(
    unsigned long long b0, unsigned long long b1,
    unsigned long long b2, unsigned long long b3, int n, int q) {
  unsigned long long bb = (n & 2) ? ((n & 1) ? b3 : b2) : ((n & 1) ? b1 : b0);
  int sh = ((n >> 2) << 4) + ((q & 1) << 3);      // q&1 keeps shift < 64
  unsigned byte = (q < 2) ? ((unsigned)(bb >> sh) & 0xFFu) : 0u;
  union { bf8 v; unsigned u[4]; } out;
#pragma unroll
  for (int jj = 0; jj < 4; ++jj) {
    unsigned two = byte >> (jj * 2);
    out.u[jj] = ((two & 1u) ? 0x3F80u : 0u) | ((two & 2u) ? 0x3F800000u : 0u);
  }
  return out.v;
}

struct SmallTab { const void* src[16]; int n[16]; int off[16]; };
struct RepTab { const void* src[8]; int Nc[8]; int NCT[8]; int lb[9]; };

// ---------------- K1: prep + repack + XcF + smalls ---------------------------
__global__ __launch_bounds__(256) void prep_all(
    const void* __restrict__ xraw, SmallTab st, RepTab rt,
    int* __restrict__ flag, float* __restrict__ CS,
    float* __restrict__ xT, float* __restrict__ sd,
    ush* __restrict__ pA, ush* __restrict__ lA,
    ush* __restrict__ PkF, ush* __restrict__ XcF, ush* __restrict__ Wf) {
  int tid = threadIdx.x;
  int fl = detect_fl(xraw, tid);
  int blk = blockIdx.x;

  if (blk < 48) {
    // ---- prep role: one thread per (b,nn) spatial row ----
    int row = blk * 256 + tid;
    int b = row / Nn, nn = row - b * Nn;
    int tile = nn >> 4, n16 = nn & 15;
    float xv[12];
#pragma unroll
    for (int t = 0; t < 12; ++t)
      xv[t] = ldraw(xraw, (size_t)(b * 12 + t) * Nn + nn, fl);
    float mx = xv[0];
#pragma unroll
    for (int t = 1; t < 12; ++t) mx = fmaxf(mx, xv[t]);
    float e[12], Z = 0.f;
#pragma unroll
    for (int t = 0; t < 12; ++t) { e[t] = expf(xv[t] - mx); Z += e[t]; }
    float invZ = 1.f / Z;
    float sacc = 0.f;
    ush pa[32], la[32];
    ush hh[4][2][8];   // [arr][half][8]: arr 0=lhi 1=llo 2=phi 3=plo
#pragma unroll
    for (int k = 0; k < 32; ++k) { pa[k] = 0; la[k] = 0; }
#pragma unroll
    for (int a2 = 0; a2 < 4; ++a2)
#pragma unroll
      for (int h = 0; h < 2; ++h)
#pragma unroll
        for (int j = 0; j < 8; ++j) hh[a2][h][j] = 0;
#pragma unroll
    for (int t = 0; t < 12; ++t) {
      float pv = e[t] * invZ;
      float lv = logf(pv + 1e-10f);
      sacc += pv * lv;
      xT[(size_t)row * 12 + t] = xv[t];
      ush phv = f2bu(pv);  float plv = pv - bu2f(phv);
      ush lhv = f2bu(lv);  float llv = lv - bu2f(lhv);
      pa[t] = phv; pa[16 + t] = f2bu(plv);
      la[t] = lhv; la[16 + t] = f2bu(llv);
      int h = t >> 3, j = t & 7;
      hh[0][h][j] = lhv;
      hh[1][h][j] = f2bu(llv);
      hh[2][h][j] = phv;
      hh[3][h][j] = f2bu(plv);
    }
    sd[row] = sacc;
    {
      uint4* d = (uint4*)(pA + (size_t)row * 32);
      const uint4* s = (const uint4*)pa;
      d[0] = s[0]; d[1] = s[1]; d[2] = s[2]; d[3] = s[3];
      uint4* d2 = (uint4*)(lA + (size_t)row * 32);
      const uint4* s2 = (const uint4*)la;
      d2[0] = s2[0]; d2[1] = s2[1]; d2[2] = s2[2]; d2[3] = s2[3];
    }
    // PkF[b][tile][arr][lane=q*16+n16] = arr-half(q&1) of this row (16B);
    // 16 lanes of a tile-group store 256B contiguous -> acceptably coalesced.
    {
      size_t tb = ((size_t)(b * 96 + tile)) * 4 * 512;
#pragma unroll
      for (int a2 = 0; a2 < 4; ++a2)
#pragma unroll
        for (int qq = 0; qq < 4; ++qq)
          *(uint4*)(PkF + tb + ((size_t)a2 * 64 + qq * 16 + n16) * 8) =
              *(const uint4*)hh[a2][qq & 1];
    }
  } else if (blk < 146) {
    // ---- repack role: weights -> MFMA B-frag order ----
    int idx = (blk - 48) * 256 + tid;
    if (idx >= rt.lb[8]) return;
    int mi = 0;
#pragma unroll
    for (int i = 1; i < 8; ++i) if (idx >= rt.lb[i]) mi = i;
    int li = idx - rt.lb[mi];
    int NCT = rt.NCT[mi], Nc = rt.Nc[mi];
    int per = NCT * 64;
    int c0 = li / per, rem = li - c0 * per;
    int ct = rem >> 6, l = rem & 63;
    int q = l >> 4, m = l & 15;
    int col = ct * 16 + m;
    ush* d = Wf + (size_t)idx * 8;
#pragma unroll
    for (int j = 0; j < 8; ++j) {
      int k = c0 * 32 + q * 8 + j;
      d[j] = (col < Nc) ? f2bu(ldraw(rt.src[mi], (size_t)k * Nc + col, fl)) : 0;
    }
  } else if (blk < 242) {
    // ---- XcF role: one thread per frag slot (b,tile,q2,nf); reads 8
    // consecutive x elems (coalesced), writes coalesced 16B frag + 16B zero.
    int idx = (blk - 146) * 256 + tid;   // 0..24575
    int b = idx / 3072, rem = idx % 3072;
    int tile = rem >> 5, r2 = rem & 31;
    int q2 = r2 >> 4, nf = r2 & 15;
    int col0 = tile * 16 + q2 * 8;
    union { ush u[8]; uint4 v; } pkv;
#pragma unroll
    for (int jj = 0; jj < 8; ++jj) {
      float v;
      if (nf < 12)      v = ldraw(xraw, (size_t)(b * 12 + nf) * Nn + col0 + jj, fl);
      else if (nf == 12) v = 1.0f;
      else               v = 0.0f;
      pkv.u[jj] = f2bu(v);
    }
    size_t xb = ((size_t)(b * 96 + tile)) * 64 * 8;
    *(uint4*)(XcF + xb + ((size_t)q2 * 16 + nf) * 8) = pkv.v;
    uint4 z4 = {0, 0, 0, 0};
    *(uint4*)(XcF + xb + ((size_t)(q2 + 2) * 16 + nf) * 8) = z4;  // q>=2 pad
  } else {
    // ---- smalls role: canonicalize biases/BN params + publish flag ----
    for (int i = 0; i < 16; ++i)
      for (int e = tid; e < st.n[i]; e += 256)
        CS[st.off[i] + e] = ldraw(st.src[i], e, fl);
    if (tid == 0) flag[0] = fl;
  }
}

// ---------------- K2: kl via MFMA (flash-style, zero LDS, coalesced) ---------
// 1536 blocks = 8 b x 24 ig x 8 js. Block 256 = 4 waves; wave owns a 16-row
// i-tile, loops 12 j-tiles. S1 = p_i . lp_j via split-bf16 (hi/lo),
// S2 = lp_i . p_j likewise. A1=(self_i-S1<.5)=A[i,j], A2=(self_j-S2<.5)
// =A[j,i]; aggregate both against X' (cols 0..11 = x, col 12 = ones ->
// row/col degrees). Mask C->A-frag via __ballot + VALU bit expansion.
// ALL inner-loop loads are lane-coalesced 1KB frag reads (PkF/XcF).
__global__ __launch_bounds__(256) void kl_mfma(
    const ush* __restrict__ pA, const ush* __restrict__ lA,
    const ush* __restrict__ PkF, const ush* __restrict__ XcF,
    const float* __restrict__ sd,
    float* __restrict__ psf, float* __restrict__ psb) {
  int tid = threadIdx.x, w = tid >> 6, l = tid & 63, q = l >> 4, n = l & 15;
  int blk = blockIdx.x;
  int b = blk / 192, rem = blk % 192, ig = rem >> 3, js = rem & 7;
  int i0 = ig * 64 + w * 16;
  int rowb = b * Nn;

  bf8 z8 = {0, 0, 0, 0, 0, 0, 0, 0};
  bf8 aP = *(const bf8*)(pA + ((size_t)(rowb + i0 + n)) * 32 + q * 8);
  bf8 aL = *(const bf8*)(lA + ((size_t)(rowb + i0 + n)) * 32 + q * 8);
  bf8 aPh = (q < 2) ? aP : z8;
  bf8 aLh = (q < 2) ? aL : z8;
  float selfI[4];
#pragma unroll
  for (int r = 0; r < 4; ++r) selfI[r] = sd[rowb + i0 + q * 4 + r];

  f4 accF = {0.f, 0.f, 0.f, 0.f}, accB = {0.f, 0.f, 0.f, 0.f};

#pragma unroll 4
  for (int jt = 0; jt < 12; ++jt) {
    int jl = js * 192 + jt * 16;
    int tile = js * 12 + jt;
    const ush* tb = PkF + ((size_t)(b * 96 + tile)) * 4 * 512 + (size_t)l * 8;
    bf8 bLh = *(const bf8*)(tb);
    bf8 bLo = *(const bf8*)(tb + 512);
    bf8 bPh = *(const bf8*)(tb + 1024);
    bf8 bPo = *(const bf8*)(tb + 1536);
    bf8 xfr = *(const bf8*)(XcF + ((size_t)(b * 96 + tile) * 64 + l) * 8);
    float selfJ = sd[rowb + jl + n];

    f4 s1 = {0.f, 0.f, 0.f, 0.f}, s2 = {0.f, 0.f, 0.f, 0.f};
    s1 = __builtin_amdgcn_mfma_f32_16x16x32_bf16(aP, bLh, s1, 0, 0, 0);
    s1 = __builtin_amdgcn_mfma_f32_16x16x32_bf16(aPh, bLo, s1, 0, 0, 0);
    s2 = __builtin_amdgcn_mfma_f32_16x16x32_bf16(aL, bPh, s2, 0, 0, 0);
    s2 = __builtin_amdgcn_mfma_f32_16x16x32_bf16(aLh, bPo, s2, 0, 0, 0);

    // v_cmp -> wave-uniform ballots: B_r bit(q*16+n) = M[q*4+r][n]
    unsigned long long f0 = __ballot(selfI[0] - s1[0] < 0.5f);
    unsigned long long f1 = __ballot(selfI[1] - s1[1] < 0.5f);
    unsigned long long f2 = __ballot(selfI[2] - s1[2] < 0.5f);
    unsigned long long f3 = __ballot(selfI[3] - s1[3] < 0.5f);
    unsigned long long g0 = __ballot(selfJ - s2[0] < 0.5f);
    unsigned long long g1 = __ballot(selfJ - s2[1] < 0.5f);
    unsigned long long g2 = __ballot(selfJ - s2[2] < 0.5f);
    unsigned long long g3 = __ballot(selfJ - s2[3] < 0.5f);

    bf8 af1 = expand_mask(f0, f1, f2, f3, n, q);
    bf8 af2 = expand_mask(g0, g1, g2, g3, n, q);
    accF = __builtin_amdgcn_mfma_f32_16x16x32_bf16(af1, xfr, accF, 0, 0, 0);
    accB = __builtin_amdgcn_mfma_f32_16x16x32_bf16(af2, xfr, accB, 0, 0, 0);
  }
#pragma unroll
  for (int r = 0; r < 4; ++r) {
    size_t o = ((size_t)js * Mrows + rowb + i0 + q * 4 + r) * 16 + n;
    psf[o] = accF[r];
    psb[o] = accB[r];
  }
}

// ---------------- K3: fused MLP, 4 waves / 16-row tile -----------------------
// z frags computed ONCE into LDS (each wave builds 6 of 24 c0-slices), reused
// by L1e and L3e -> z-VALU cut 8x vs regen-per-use. LDS frag layout
// (lane-major): slot(c0, l)*8+j holds A[m=l&15][k=(l>>4)*8+j]. Wave w handles
// col-tiles {2w,2w+1} for N=128 layers, {w} for N=64, K-split for N=12 tail.
__global__ __launch_bounds__(256) void fused_mlp(
    const float* __restrict__ xT,
    const float* __restrict__ psf, const float* __restrict__ psb,
    const float* __restrict__ CS, const ush* __restrict__ Wf,
    const int* __restrict__ flag, void* __restrict__ outp) {
  __shared__ float xs[16][12], ccs[16][12];
  __shared__ float sfs[16][16], sbs[16][16];
  __shared__ float ws1[64], ws2[64];
  __shared__ ush zf[24 * 512];   // z frags, K=768 (24 KB)
  __shared__ ush hf[2048], hg[2048], xf[1024];
  __shared__ f4 red[4][64];

  int tid = threadIdx.x, w = tid >> 6, l = tid & 63, q = l >> 4, n = l & 15;
  int r0 = blockIdx.x * 16;

  // --- init: xs, W1/W2, and kl-partial reduction -> sfs/sbs ----------------
  {
    int r = tid >> 4, t = tid & 15;
    float a = 0.f, b = 0.f;
#pragma unroll
    for (int js = 0; js < JS; ++js) {
      size_t o = ((size_t)js * Mrows + r0 + r) * 16 + t;
      a += psf[o];
      b += psb[o];
    }
    sfs[r][t] = a;
    sbs[r][t] = b;
    if (tid < 128) { if (tid < 64) ws1[tid] = CS[tid]; else ws2[tid - 64] = CS[tid]; }
    if (tid < 192) {
      int rr = tid / 12, tt = tid - rr * 12;
      xs[rr][tt] = xT[(size_t)(r0 + rr) * 12 + tt];
    }
  }
  __syncthreads();
  if (tid < 192) {
    int rr = tid / 12, tt = tid - rr * 12;
    float irs = 1.f / fmaxf(sfs[rr][12], 1e-6f);
    float ics = 1.f / fmaxf(sbs[rr][12], 1e-6f);
    ccs[rr][tt] = 3.0f * (0.3f * sfs[rr][tt] * irs + 0.7f * sbs[rr][tt] * ics);
  }
  __syncthreads();

  // --- phase Z: z frags once into LDS; wave w builds c0 = 6w .. 6w+5 -------
  {
#pragma unroll
    for (int cc = 0; cc < 6; ++cc) {
      int c0 = w * 6 + cc;
      int t = c0 >> 1, h0 = (c0 & 1) * 32 + q * 8;
      float xv = xs[n][t], cv = ccs[n][t];
      union { uint4 v; ush u[8]; } au;
#pragma unroll
      for (int j = 0; j < 8; ++j)
        au.u[j] = f2bu(fmaxf(fmaf(xv, ws1[h0 + j], cv * ws2[h0 + j]), 0.f));
      *(uint4*)(&zf[(size_t)(c0 * 64 + l) * 8]) = au.v;
    }
  }
  __syncthreads();

  // C-layout -> frag-slot store position for col-tile ct
  auto fpos = [&](int ct, int r) -> int {
    return ((ct >> 1) * 64 + ((ct & 1) * 2 + (n >> 3)) * 16 + q * 4 + r) * 8 + (n & 7);
  };

  // --- L1e: h1 = relu(z @ ew1 + b1), N=128, wave does ct = 2w, 2w+1 --------
  {
    f4 a0 = {0.f, 0.f, 0.f, 0.f}, a1 = {0.f, 0.f, 0.f, 0.f};
    for (int c0 = 0; c0 < 24; ++c0) {
      bf8 a = *(const bf8*)(&zf[(size_t)(c0 * 64 + l) * 8]);
      const ush* wb = Wf + ((size_t)(c0 * 8 + 2 * w) * 64 + l) * 8;
      bf8 b0 = *(const bf8*)wb;
      bf8 b1 = *(const bf8*)(wb + 512);
      a0 = __builtin_amdgcn_mfma_f32_16x16x32_bf16(a, b0, a0, 0, 0, 0);
      a1 = __builtin_amdgcn_mfma_f32_16x16x32_bf16(a, b1, a1, 0, 0, 0);
    }
#pragma unroll
    for (int u2 = 0; u2 < 2; ++u2) {
      int ct = 2 * w + u2;
      f4 acc = u2 ? a1 : a0;
      float bz = CS[128 + ct * 16 + n];
#pragma unroll
      for (int r = 0; r < 4; ++r)
        hf[fpos(ct, r)] = f2bu(fmaxf(acc[r] + bz, 0.f));
    }
  }
  __syncthreads();

  // --- L2e: h2 = relu(h1 @ ew2 + b2), K=128 --------------------------------
  {
    f4 a0 = {0.f, 0.f, 0.f, 0.f}, a1 = {0.f, 0.f, 0.f, 0.f};
    for (int c0 = 0; c0 < 4; ++c0) {
      bf8 a = *(const bf8*)(&hf[(size_t)(c0 * 64 + l) * 8]);
      const ush* wb = Wf + 98304 + ((size_t)(c0 * 8 + 2 * w) * 64 + l) * 8;
      bf8 b0 = *(const bf8*)wb;
      bf8 b1 = *(const bf8*)(wb + 512);
      a0 = __builtin_amdgcn_mfma_f32_16x16x32_bf16(a, b0, a0, 0, 0, 0);
      a1 = __builtin_amdgcn_mfma_f32_16x16x32_bf16(a, b1, a1, 0, 0, 0);
    }
#pragma unroll
    for (int u2 = 0; u2 < 2; ++u2) {
      int ct = 2 * w + u2;
      f4 acc = u2 ? a1 : a0;
      float bz = CS[256 + ct * 16 + n];
#pragma unroll
      for (int r = 0; r < 4; ++r)
        hg[fpos(ct, r)] = f2bu(fmaxf(acc[r] + bz, 0.f));
    }
  }
  __syncthreads();

  // --- L3e: xe = BN(h2 @ ew3 + b3 + z @ eproj), N=64, wave does ct = w -----
  {
    f4 a3 = {0.f, 0.f, 0.f, 0.f};
    for (int c0 = 0; c0 < 4; ++c0) {
      bf8 a = *(const bf8*)(&hg[(size_t)(c0 * 64 + l) * 8]);
      bf8 b = *(const bf8*)(Wf + 114688 + ((size_t)(c0 * 4 + w) * 64 + l) * 8);
      a3 = __builtin_amdgcn_mfma_f32_16x16x32_bf16(a, b, a3, 0, 0, 0);
    }
    for (int c0 = 0; c0 < 24; ++c0) {
      bf8 a = *(const bf8*)(&zf[(size_t)(c0 * 64 + l) * 8]);
      bf8 b = *(const bf8*)(Wf + 122880 + ((size_t)(c0 * 4 + w) * 64 + l) * 8);
      a3 = __builtin_amdgcn_mfma_f32_16x16x32_bf16(a, b, a3, 0, 0, 0);
    }
    int col = w * 16 + n;
    float g = CS[448 + col], be = CS[512 + col], mm = CS[576 + col], vv = CS[640 + col];
    float sc = g / sqrtf(vv + 1e-5f);
    float sh = be - mm * sc;
    float bz = CS[384 + col];
#pragma unroll
    for (int r = 0; r < 4; ++r)
      xf[fpos(w, r)] = f2bu((a3[r] + bz) * sc + sh);
  }
  __syncthreads();

  // --- L1d: g1 = relu(xe @ dw1 + b1), K=64, N=128 --------------------------
  {
    f4 a0 = {0.f, 0.f, 0.f, 0.f}, a1 = {0.f, 0.f, 0.f, 0.f};
    for (int c0 = 0; c0 < 2; ++c0) {
      bf8 a = *(const bf8*)(&xf[(size_t)(c0 * 64 + l) * 8]);
      const ush* wb = Wf + 172032 + ((size_t)(c0 * 8 + 2 * w) * 64 + l) * 8;
      bf8 b0 = *(const bf8*)wb;
      bf8 b1 = *(const bf8*)(wb + 512);
      a0 = __builtin_amdgcn_mfma_f32_16x16x32_bf16(a, b0, a0, 0, 0, 0);
      a1 = __builtin_amdgcn_mfma_f32_16x16x32_bf16(a, b1, a1, 0, 0, 0);
    }
    __syncthreads();   // hf rewrite fence (L2e reads of hf are complete)
#pragma unroll
    for (int u2 = 0; u2 < 2; ++u2) {
      int ct = 2 * w + u2;
      f4 acc = u2 ? a1 : a0;
      float bz = CS[704 + ct * 16 + n];
#pragma unroll
      for (int r = 0; r < 4; ++r)
        hf[fpos(ct, r)] = f2bu(fmaxf(acc[r] + bz, 0.f));
    }
  }
  __syncthreads();

  // --- L2d: g2 = relu(g1 @ dw2 + b2), K=128 --------------------------------
  {
    f4 a0 = {0.f, 0.f, 0.f, 0.f}, a1 = {0.f, 0.f, 0.f, 0.f};
    for (int c0 = 0; c0 < 4; ++c0) {
      bf8 a = *(const bf8*)(&hf[(size_t)(c0 * 64 + l) * 8]);
      const ush* wb = Wf + 180224 + ((size_t)(c0 * 8 + 2 * w) * 64 + l) * 8;
      bf8 b0 = *(const bf8*)wb;
      bf8 b1 = *(const bf8*)(wb + 512);
      a0 = __builtin_amdgcn_mfma_f32_16x16x32_bf16(a, b0, a0, 0, 0, 0);
      a1 = __builtin_amdgcn_mfma_f32_16x16x32_bf16(a, b1, a1, 0, 0, 0);
    }
    __syncthreads();   // hg rewrite fence
#pragma unroll
    for (int u2 = 0; u2 < 2; ++u2) {
      int ct = 2 * w + u2;
      f4 acc = u2 ? a1 : a0;
      float bz = CS[832 + ct * 16 + n];
#pragma unroll
      for (int r = 0; r < 4; ++r)
        hg[fpos(ct, r)] = f2bu(fmaxf(acc[r] + bz, 0.f));
    }
  }
  __syncthreads();

  // --- L3d: out = BN(g2 @ dw3 + b3 + xe @ dproj), N=12; K-split 4 waves ----
  {
    f4 ao = {0.f, 0.f, 0.f, 0.f};
    {  // dw3 chunk c0 = w  (K=128 -> 4 chunks)
      bf8 a = *(const bf8*)(&hg[(size_t)(w * 64 + l) * 8]);
      bf8 b = *(const bf8*)(Wf + 196608 + ((size_t)w * 64 + l) * 8);
      ao = __builtin_amdgcn_mfma_f32_16x16x32_bf16(a, b, ao, 0, 0, 0);
    }
    if (w < 2) {  // dproj chunk c0 = w  (K=64 -> 2 chunks)
      bf8 a = *(const bf8*)(&xf[(size_t)(w * 64 + l) * 8]);
      bf8 b = *(const bf8*)(Wf + 198656 + ((size_t)w * 64 + l) * 8);
      ao = __builtin_amdgcn_mfma_f32_16x16x32_bf16(a, b, ao, 0, 0, 0);
    }
    red[w][l] = ao;
  }
  __syncthreads();
  if (w == 0) {
    f4 s = red[0][l] + red[1][l] + red[2][l] + red[3][l];
    int fl = flag[0];
    if (n < 12) {
      float bz = CS[960 + n];
      float g = CS[972 + n], be = CS[984 + n], mm = CS[996 + n], vv = CS[1008 + n];
      float sc = g / sqrtf(vv + 1e-5f);
      float sh = be - mm * sc;
#pragma unroll
      for (int r = 0; r < 4; ++r) {
        int row = r0 + q * 4 + r;
        int bb = row / Nn, nn = row - bb * Nn;
        size_t oi = ((size_t)bb * TOUT + n) * Nn + nn;
        float ov = (s[r] + bz) * sc + sh;
        if (fl) ((float*)outp)[oi] = ov;
        else    ((ush*)outp)[oi] = f2bu(ov);
      }
    }
  }
}

}  // namespace

extern "C" void kernel_launch(void* const* d_in, const int* in_sizes, int n_in,
                              void* d_out, int out_size, void* d_ws, size_t ws_size,
                              hipStream_t stream) {
  float* f = (float*)d_ws;
  int* flag = (int*)d_ws;                 // f[0..15]
  float* CS  = f + 16;                    // 1020 small params (f32)
  float* xT  = f + 1040;                  // 147456
  float* sd  = f + 148496;                // 12288
  float* psf = f + 160784;                // 8*12288*16 = 1572864
  float* psb = f + 1733648;               // 1572864
  ush* U = (ush*)(f + 3306512);
  ush* pA    = U;                         // 12288*32
  ush* lA    = U + 393216;                // 12288*32
  ush* PkF   = U + 786432;                // 8*96*4*512 = 1572864
  ush* XcF   = U + 2359296;               // 8*96*512   = 393216
  ush* Wf    = U + 2752512;               // 199680

  SmallTab st;
  {
    const int idxs[16] = {1, 2, 4, 6, 8, 10, 11, 12, 13, 15, 17, 19, 21, 22, 23, 24};
    const int ns[16]   = {64, 64, 128, 128, 64, 64, 64, 64, 64, 128, 128, 12, 12, 12, 12, 12};
    int off = 0;
    for (int i = 0; i < 16; ++i) {
      st.src[i] = d_in[idxs[i]]; st.n[i] = ns[i]; st.off[i] = off; off += ns[i];
    }
  }
  RepTab rt;
  {
    const int idxs[8]  = {3, 5, 7, 9, 14, 16, 18, 20};
    const int rNc[8]   = {128, 128, 64, 64, 128, 128, 12, 12};
    const int rNCT[8]  = {8, 8, 4, 4, 8, 8, 1, 1};
    const int rlb[9]   = {0, 12288, 14336, 15360, 21504, 22528, 24576, 24832, 24960};
    for (int i = 0; i < 8; ++i) {
      rt.src[i] = d_in[idxs[i]]; rt.Nc[i] = rNc[i]; rt.NCT[i] = rNCT[i];
    }
    for (int i = 0; i < 9; ++i) rt.lb[i] = rlb[i];
  }

  prep_all<<<243, 256, 0, stream>>>(d_in[0], st, rt, flag, CS, xT, sd,
                                    pA, lA, PkF, XcF, Wf);
  kl_mfma<<<1536, 256, 0, stream>>>(pA, lA, PkF, XcF, sd, psf, psb);
  fused_mlp<<<768, 256, 0, stream>>>(xT, psf, psb, CS, Wf, flag, d_out);
}